// Round 3
// baseline (1051.158 us; speedup 1.0000x reference)
//
#include <hip/hip_runtime.h>
#include <hip/hip_bf16.h>

// Problem constants
#define BB 256
#define PP 20
#define HH 4
#define FF 1024
#define LL 300
#define SS 16
#define HDIM 1024
#define CC 117
#define NNODE (BB * PP)              // 5120
#define NREAD (BB * (PP * HH - HH))  // 19456

// ---------------------------------------------------------------------------
// Dtype sniff: interpret first 512 half-words of `buf` as bf16. True bf16
// N(0,1) data -> ~512/512 magnitudes in [2^-30, 2^30]. fp32 data read as
// bf16 -> low half-words have uniform-random exponents -> only ~315/512.
// flag[0] = 1 means "inputs are fp32".
// ---------------------------------------------------------------------------
__global__ void sniff_dtype(const unsigned short* __restrict__ buf,
                            int* __restrict__ flag) {
  int t = threadIdx.x;
  int votes = 0;
  for (int i = t; i < 512; i += 256) {
    unsigned int u = (unsigned int)buf[i] << 16;
    float v = __uint_as_float(u);
    float a = fabsf(v);
    if (v == v && a > 9.3e-10f && a < 1.1e9f) votes++;
  }
  __shared__ int sv[256];
  sv[t] = votes;
  __syncthreads();
  for (int s = 128; s > 0; s >>= 1) {
    if (t < s) sv[t] += sv[t + s];
    __syncthreads();
  }
  if (t == 0) flag[0] = (sv[0] < 448) ? 1 : 0;
}

// Canonicalize any float input to bf16, branching on the sniffed dtype.
__global__ __launch_bounds__(256) void convert_in(
    const void* __restrict__ src, __hip_bfloat16* __restrict__ dst, int n,
    const int* __restrict__ flag) {
  int i = blockIdx.x * 256 + threadIdx.x;
  if (i >= n) return;
  if (flag[0]) {
    dst[i] = __float2bfloat16(((const float*)src)[i]);
  } else {
    dst[i] = ((const __hip_bfloat16*)src)[i];
  }
}

// ---------------------------------------------------------------------------
// Generic bf16 GEMM: C[M,N] = A[M,K] @ B[K,N] (+bias, +relu), fp32 accumulate.
// c_mode: 0 = bf16 store, 1 = fp32 store, 2 = branch on outflag[0] (1->fp32).
// row_mode gathers human rows: m -> (m>>2)*PP + (m&3).
// ---------------------------------------------------------------------------
#define BM 64
#define BN 64
#define BK 16

__global__ __launch_bounds__(256) void gemm_bf16(
    const __hip_bfloat16* __restrict__ A, const __hip_bfloat16* __restrict__ B,
    void* __restrict__ Cout, const __hip_bfloat16* __restrict__ bias,
    int M, int N, int K, int ldb, int row_mode, int do_relu, int c_mode,
    const int* __restrict__ outflag) {
  __shared__ float As[BK][BM + 4];
  __shared__ float Bs[BK][BN + 4];
  const int tid = threadIdx.x;
  const int n0 = blockIdx.x * BN;
  const int m0 = blockIdx.y * BM;
  const int tx = tid & 15;
  const int ty = tid >> 4;
  float acc[4][4] = {};

  for (int k0 = 0; k0 < K; k0 += BK) {
#pragma unroll
    for (int i = 0; i < 4; i++) {
      int l = tid * 4 + i;
      int r = l >> 4, kk = l & 15;
      int m = m0 + r;
      int k = k0 + kk;
      float v = 0.f;
      if (m < M && k < K) {
        int mm = row_mode ? ((m >> 2) * PP + (m & 3)) : m;
        v = __bfloat162float(A[(long)mm * K + k]);
      }
      As[kk][r] = v;
    }
#pragma unroll
    for (int i = 0; i < 4; i++) {
      int l = tid * 4 + i;
      int kk = l >> 6, n = l & 63;
      int k = k0 + kk;
      int nn = n0 + n;
      float v = 0.f;
      if (k < K && nn < N) v = __bfloat162float(B[(long)k * ldb + nn]);
      Bs[kk][n] = v;
    }
    __syncthreads();
#pragma unroll
    for (int kk = 0; kk < BK; kk++) {
      float a[4], b[4];
#pragma unroll
      for (int i = 0; i < 4; i++) a[i] = As[kk][ty * 4 + i];
#pragma unroll
      for (int j = 0; j < 4; j++) b[j] = Bs[kk][tx * 4 + j];
#pragma unroll
      for (int i = 0; i < 4; i++)
#pragma unroll
        for (int j = 0; j < 4; j++) acc[i][j] += a[i] * b[j];
    }
    __syncthreads();
  }

  int store_f32 = (c_mode == 1) || (c_mode == 2 && outflag && outflag[0]);
#pragma unroll
  for (int i = 0; i < 4; i++) {
    int m = m0 + ty * 4 + i;
    if (m >= M) continue;
#pragma unroll
    for (int j = 0; j < 4; j++) {
      int n = n0 + tx * 4 + j;
      if (n >= N) continue;
      float v = acc[i][j];
      if (bias) v += __bfloat162float(bias[n]);
      if (do_relu) v = fmaxf(v, 0.f);
      if (store_f32)
        ((float*)Cout)[(long)m * N + n] = v;
      else
        ((__hip_bfloat16*)Cout)[(long)m * N + n] = __float2bfloat16(v);
    }
  }
}

// ---------------------------------------------------------------------------
// Per-node attention logits: es[n] = h[n,:].a[0:D], ed[n] = h[n,:].a[D:2D]
// ---------------------------------------------------------------------------
template <int DIM>
__global__ __launch_bounds__(256) void edge_logits(
    const float* __restrict__ h, const __hip_bfloat16* __restrict__ a,
    float* __restrict__ es, float* __restrict__ ed) {
  const int n = blockIdx.x;
  const int t = threadIdx.x;
  float s1 = 0.f, s2 = 0.f;
  for (int f = t; f < DIM; f += 256) {
    float hv = h[(long)n * DIM + f];
    s1 += hv * __bfloat162float(a[f]);
    s2 += hv * __bfloat162float(a[DIM + f]);
  }
#pragma unroll
  for (int off = 32; off > 0; off >>= 1) {
    s1 += __shfl_down(s1, off);
    s2 += __shfl_down(s2, off);
  }
  __shared__ float r1[4], r2[4];
  int lane = t & 63, wid = t >> 6;
  if (lane == 0) { r1[wid] = s1; r2[wid] = s2; }
  __syncthreads();
  if (t == 0) {
    es[n] = r1[0] + r1[1] + r1[2] + r1[3];
    ed[n] = r2[0] + r2[1] + r2[2] + r2[3];
  }
}

// ---------------------------------------------------------------------------
// GAT update per dst node. All __syncthreads() wave-uniform at top level.
// ---------------------------------------------------------------------------
template <int DIM>
__global__ __launch_bounds__(256) void attn_update(
    const __hip_bfloat16* __restrict__ x, const float* __restrict__ h,
    const float* __restrict__ es, const float* __restrict__ ed,
    __hip_bfloat16* __restrict__ out) {
  const int n = blockIdx.x;
  const int b = n / PP, d = n % PP;
  const int t = threadIdx.x;
  __shared__ float logit[PP];
  __shared__ float alpha[PP];
  __shared__ float red[2];

  if (t < PP) {
    float e;
    if (t == d) {
      e = -1e30f;                    // self-edge excluded: exp -> 0
    } else {
      float v = es[b * PP + t] + ed[n];
      e = (v > 0.f) ? v : 0.2f * v;  // leaky_relu 0.2
    }
    logit[t] = e;
  }
  __syncthreads();
  if (t == 0) {
    float m = -1e30f;
    for (int s = 0; s < PP; s++) m = fmaxf(m, logit[s]);
    float sum = 0.f;
    for (int s = 0; s < PP; s++) sum += expf(logit[s] - m);
    red[0] = m;
    red[1] = sum;
  }
  __syncthreads();
  if (t < PP) alpha[t] = expf(logit[t] - red[0]) / (red[1] + 1e-9f);
  __syncthreads();

  for (int f = t; f < DIM; f += 256) {
    float acc = 0.f;
#pragma unroll
    for (int s = 0; s < PP; s++)
      acc += alpha[s] * h[(long)(b * PP + s) * DIM + f];
    float v = __bfloat162float(x[(long)n * DIM + f]) + acc;
    out[(long)n * DIM + f] = __float2bfloat16(v > 0.f ? v : 0.f);
  }
}

// ---------------------------------------------------------------------------
// Combine per readout edge: hdn[e,:] = relu(Yd_v[hd] + Yd_l[hd] + Ys_v[s] +
//   Ys_l[s] + sf@W1sp + b1), stored bf16. Y arrays are bf16.
// ---------------------------------------------------------------------------
__global__ __launch_bounds__(256) void combine_kernel(
    const int* __restrict__ edge_src, const int* __restrict__ edge_dst,
    const int* __restrict__ readout_eid,
    const __hip_bfloat16* __restrict__ spatial,
    const __hip_bfloat16* __restrict__ W1sp,  // W1 + 1324*HDIM
    const __hip_bfloat16* __restrict__ b1,
    const __hip_bfloat16* __restrict__ Yd_v,
    const __hip_bfloat16* __restrict__ Yd_l,
    const __hip_bfloat16* __restrict__ Ys_v,
    const __hip_bfloat16* __restrict__ Ys_l,
    __hip_bfloat16* __restrict__ hdn) {
  const int e = blockIdx.x;
  const int re = readout_eid[e];
  const int s = edge_src[re];
  const int d = edge_dst[re];
  const int hidx = (d / PP) * HH + (d % PP);  // human-node compact index
  const int t = threadIdx.x;
  __shared__ float sf[SS];
  if (t < SS) sf[t] = __bfloat162float(spatial[(long)re * SS + t]);
  __syncthreads();
  for (int hd = t; hd < HDIM; hd += 256) {
    float v = __bfloat162float(Yd_v[(long)hidx * HDIM + hd]) +
              __bfloat162float(Yd_l[(long)hidx * HDIM + hd]) +
              __bfloat162float(Ys_v[(long)s * HDIM + hd]) +
              __bfloat162float(Ys_l[(long)s * HDIM + hd]) +
              __bfloat162float(b1[hd]);
#pragma unroll
    for (int k = 0; k < SS; k++)
      v += sf[k] * __bfloat162float(W1sp[(long)k * HDIM + hd]);
    hdn[(long)e * HDIM + hd] = __float2bfloat16(v > 0.f ? v : 0.f);
  }
}

// ---------------------------------------------------------------------------
extern "C" void kernel_launch(void* const* d_in, const int* in_sizes, int n_in,
                              void* d_out, int out_size, void* d_ws,
                              size_t ws_size, hipStream_t stream) {
  const int* e_src = (const int*)d_in[11];
  const int* e_dst = (const int*)d_in[12];
  const int* r_eid = (const int*)d_in[13];
  (void)ws_size; (void)n_in; (void)in_sizes; (void)out_size;

  char* ws = (char*)d_ws;
  size_t off = 0;
  auto take = [&](size_t bytes) {
    char* p = ws + off;
    off += (bytes + 255) & ~(size_t)255;
    return p;
  };

  // dtype flag
  int* dflag = (int*)take(256);
  // canonical bf16 copies of all float inputs (~24.7 MB)
  __hip_bfloat16* cF  = (__hip_bfloat16*)take((size_t)NNODE * FF * 2);
  __hip_bfloat16* cL  = (__hip_bfloat16*)take((size_t)NNODE * LL * 2);
  __hip_bfloat16* cSp = (__hip_bfloat16*)take((size_t)BB * PP * (PP - 1) * SS * 2);
  __hip_bfloat16* cWv = (__hip_bfloat16*)take((size_t)FF * FF * 2);
  __hip_bfloat16* cAv = (__hip_bfloat16*)take((size_t)2 * FF * 2);
  __hip_bfloat16* cWl = (__hip_bfloat16*)take((size_t)LL * LL * 2);
  __hip_bfloat16* cAl = (__hip_bfloat16*)take((size_t)2 * LL * 2);
  __hip_bfloat16* cW1 = (__hip_bfloat16*)take((size_t)2664 * HDIM * 2);
  __hip_bfloat16* cB1 = (__hip_bfloat16*)take((size_t)HDIM * 2);
  __hip_bfloat16* cW2 = (__hip_bfloat16*)take((size_t)HDIM * CC * 2);
  __hip_bfloat16* cB2 = (__hip_bfloat16*)take((size_t)CC * 2);

  // seg1 overlay: phase A (h_v/h_l fp32 + logits) then phase B (Y arrays bf16)
  const size_t PHASE_A = (size_t)NNODE * FF * 4 + (size_t)NNODE * LL * 4 +
                         4 * (size_t)NNODE * 4;  // 27,197,440
  char* seg1 = take(PHASE_A);
  float* h_v = (float*)seg1;
  float* h_l = (float*)(seg1 + (size_t)NNODE * FF * 4);
  float* es_v = (float*)(seg1 + (size_t)NNODE * FF * 4 + (size_t)NNODE * LL * 4);
  float* ed_v = es_v + NNODE;
  float* es_l = ed_v + NNODE;
  float* ed_l = es_l + NNODE;
  __hip_bfloat16* Yd_v = (__hip_bfloat16*)seg1;               // phase B overlay
  __hip_bfloat16* Yd_l = Yd_v + (size_t)BB * HH * HDIM;
  __hip_bfloat16* Ys_v = Yd_l + (size_t)BB * HH * HDIM;
  __hip_bfloat16* Ys_l = Ys_v + (size_t)NNODE * HDIM;          // ends 25.2 MB

  __hip_bfloat16* new_f = (__hip_bfloat16*)take((size_t)NNODE * FF * 2);
  __hip_bfloat16* new_l = (__hip_bfloat16*)take((size_t)NNODE * LL * 2);
  __hip_bfloat16* hdn = (__hip_bfloat16*)take((size_t)NREAD * HDIM * 2);

  dim3 blk(256);

  // 0) sniff input dtype from feat
  sniff_dtype<<<1, blk, 0, stream>>>((const unsigned short*)d_in[0], dflag);

  // 0b) canonicalize all float inputs to bf16
  auto conv = [&](int idx, __hip_bfloat16* dst, int n) {
    convert_in<<<(n + 255) / 256, blk, 0, stream>>>(d_in[idx], dst, n, dflag);
  };
  conv(0, cF, NNODE * FF);
  conv(1, cL, NNODE * LL);
  conv(2, cSp, BB * PP * (PP - 1) * SS);
  conv(3, cWv, FF * FF);
  conv(4, cAv, 2 * FF);
  conv(5, cWl, LL * LL);
  conv(6, cAl, 2 * LL);
  conv(7, cW1, 2664 * HDIM);
  conv(8, cB1, HDIM);
  conv(9, cW2, HDIM * CC);
  conv(10, cB2, CC);

  auto gemm = [&](const __hip_bfloat16* A, const __hip_bfloat16* B, void* C,
                  const __hip_bfloat16* bias, int M, int N, int K, int ldb,
                  int row_mode, int relu, int c_mode, const int* oflag) {
    dim3 grid((N + BN - 1) / BN, (M + BM - 1) / BM);
    gemm_bf16<<<grid, blk, 0, stream>>>(A, B, C, bias, M, N, K, ldb, row_mode,
                                        relu, c_mode, oflag);
  };

  // 1) Projections h = x @ W (fp32 out)
  gemm(cF, cWv, h_v, nullptr, NNODE, FF, FF, FF, 0, 0, 1, nullptr);
  gemm(cL, cWl, h_l, nullptr, NNODE, LL, LL, LL, 0, 0, 1, nullptr);

  // 2) Attention logits per node
  edge_logits<FF><<<NNODE, blk, 0, stream>>>(h_v, cAv, es_v, ed_v);
  edge_logits<LL><<<NNODE, blk, 0, stream>>>(h_l, cAl, es_l, ed_l);

  // 3) GAT update (segment softmax + message + residual relu)
  attn_update<FF><<<NNODE, blk, 0, stream>>>(cF, h_v, es_v, ed_v, new_f);
  attn_update<LL><<<NNODE, blk, 0, stream>>>(cL, h_l, es_l, ed_l, new_l);

  // 4) Decomposed x@W1 per-node projections (bf16 out, overlays phase A).
  //    W1 rows: [0,1024) dstV | [1024,1324) dstL | [1324,1340) spatial |
  //             [1340,1640) srcL | [1640,2664) srcV
  gemm(new_f, cW1, Yd_v, nullptr, BB * HH, HDIM, FF, HDIM, 1, 0, 0, nullptr);
  gemm(new_l, cW1 + (size_t)1024 * HDIM, Yd_l, nullptr, BB * HH, HDIM, LL,
       HDIM, 1, 0, 0, nullptr);
  gemm(new_l, cW1 + (size_t)1340 * HDIM, Ys_l, nullptr, NNODE, HDIM, LL, HDIM,
       0, 0, 0, nullptr);
  gemm(new_f, cW1 + (size_t)1640 * HDIM, Ys_v, nullptr, NNODE, HDIM, FF, HDIM,
       0, 0, 0, nullptr);

  // 5) Per-readout-edge combine + relu -> hdn (bf16)
  combine_kernel<<<NREAD, blk, 0, stream>>>(e_src, e_dst, r_eid, cSp,
                                            cW1 + (size_t)1324 * HDIM, cB1,
                                            Yd_v, Yd_l, Ys_v, Ys_l, hdn);

  // 6) out = hdn @ W2 + b2; output dtype per sniffed flag
  gemm(hdn, cW2, d_out, cB2, NREAD, CC, HDIM, CC, 0, 0, 2, dflag);
}

// Round 4
// 437.205 us; speedup vs baseline: 2.4043x; 2.4043x over previous
//
#include <hip/hip_runtime.h>
#include <hip/hip_bf16.h>

// Problem constants
#define BB 256
#define PP 20
#define HH 4
#define FF 1024
#define LL 300
#define LLP 320   // LL padded to multiple of 32 for MFMA K-loop
#define SS 16
#define HDIM 1024
#define CC 117
#define NNODE (BB * PP)              // 5120
#define NREAD (BB * (PP * HH - HH))  // 19456

typedef __attribute__((ext_vector_type(8))) short bf16x8v;  // 8 bf16 = 4 VGPRs
typedef __attribute__((ext_vector_type(4))) float f32x4v;

// ---------------------------------------------------------------------------
// Dtype sniff: bf16 N(0,1) data -> ~512/512 magnitudes in [2^-30,2^30];
// fp32 read as bf16 -> only ~61% (low half-words have random exponents).
// flag[0] = 1 means "inputs are fp32".
// ---------------------------------------------------------------------------
__global__ void sniff_dtype(const unsigned short* __restrict__ buf,
                            int* __restrict__ flag) {
  int t = threadIdx.x;
  int votes = 0;
  for (int i = t; i < 512; i += 256) {
    unsigned int u = (unsigned int)buf[i] << 16;
    float v = __uint_as_float(u);
    float a = fabsf(v);
    if (v == v && a > 9.3e-10f && a < 1.1e9f) votes++;
  }
  __shared__ int sv[256];
  sv[t] = votes;
  __syncthreads();
  for (int s = 128; s > 0; s >>= 1) {
    if (t < s) sv[t] += sv[t + s];
    __syncthreads();
  }
  if (t == 0) flag[0] = (sv[0] < 448) ? 1 : 0;
}

// ---------------------------------------------------------------------------
// Flat convert with optional column padding: dst[R x Cp] (bf16) from
// src block starting at row0, R x C, leading dim ld. Pad cols with 0.
// ---------------------------------------------------------------------------
__global__ __launch_bounds__(256) void convert_pad(
    const void* __restrict__ src, __hip_bfloat16* __restrict__ dst, long row0,
    int R, int C, int ld, int Cp, const int* __restrict__ flag) {
  long i = (long)blockIdx.x * 256 + threadIdx.x;
  long total = (long)R * Cp;
  if (i >= total) return;
  int r = (int)(i / Cp), c = (int)(i % Cp);
  float v = 0.f;
  if (c < C) {
    long idx = (row0 + r) * (long)ld + c;
    v = flag[0] ? ((const float*)src)[idx]
                : __bfloat162float(((const __hip_bfloat16*)src)[idx]);
  }
  dst[i] = __float2bfloat16(v);
}

// ---------------------------------------------------------------------------
// Transposed convert: dst[N x Kp] (bf16, row-major, = B^T) from src block
// rows [row0, row0+K) x N cols, leading dim ld. K-pad with zeros.
// 32x32 LDS tile, 256 threads (32x8).
// ---------------------------------------------------------------------------
__global__ __launch_bounds__(256) void convert_transpose(
    const void* __restrict__ src, __hip_bfloat16* __restrict__ dst, long row0,
    int K, int N, int ld, int Kp, const int* __restrict__ flag) {
  __shared__ float tile[32][33];
  int kb = blockIdx.x * 32, nb = blockIdx.y * 32;
  int tx = threadIdx.x & 31, ty = threadIdx.x >> 5;  // ty 0..7
  for (int i = ty; i < 32; i += 8) {
    int k = kb + i, n = nb + tx;
    float v = 0.f;
    if (k < K && n < N) {
      long idx = (row0 + k) * (long)ld + n;
      v = flag[0] ? ((const float*)src)[idx]
                  : __bfloat162float(((const __hip_bfloat16*)src)[idx]);
    }
    tile[i][tx] = v;
  }
  __syncthreads();
  for (int i = ty; i < 32; i += 8) {
    int n = nb + i, k = kb + tx;
    if (n < N && k < Kp) dst[(long)n * Kp + k] = __float2bfloat16(tile[tx][i]);
  }
}

// ---------------------------------------------------------------------------
// MFMA GEMM (m97 structure): C[M,N] = A[M,K] @ B[K,N], B given TRANSPOSED as
// BT[N,K]. 128x128 tile, BK=32, 4 waves each computing a 64x64 quadrant as a
// 4x4 grid of 16x16x32 bf16 MFMAs. Staging via global_load_lds width=16
// (LDS layout = lane-ordered contiguous, NO padding — m104 caveat).
// row_mode=1 gathers A rows: r -> (r>>2)*PP + (r&3) (human-node compact).
// c_mode: 0 bf16 store, 1 fp32 store, 2 branch on outflag[0] (1->fp32).
// Requires: K % 32 == 0, lda/ldbt even, 16B-aligned base pointers.
// ---------------------------------------------------------------------------
#define TM 128
#define TN 128
#define TK 32

__global__ __launch_bounds__(256) void gemm_mfma_bt(
    const __hip_bfloat16* __restrict__ A, const __hip_bfloat16* __restrict__ BT,
    void* __restrict__ Cout, const __hip_bfloat16* __restrict__ bias, int M,
    int N, int K, int lda, int ldbt, int ldc, int row_mode, int do_relu,
    int c_mode, const int* __restrict__ outflag) {
  __shared__ __hip_bfloat16 Asm[TM * TK];  // 8 KB, rows of 32 bf16 (64 B)
  __shared__ __hip_bfloat16 Bsm[TN * TK];  // 8 KB
  const int tid = threadIdx.x;
  const int lane = tid & 63;
  const int wave = tid >> 6;
  const int wm = (wave & 1) * 64;   // wave's M quadrant
  const int wn = (wave >> 1) * 64;  // wave's N quadrant
  const int m0 = blockIdx.y * TM;
  const int n0 = blockIdx.x * TN;
  const int col_l = lane & 15;
  const int quad = lane >> 4;

  f32x4v acc[4][4];
#pragma unroll
  for (int i = 0; i < 4; i++)
#pragma unroll
    for (int j = 0; j < 4; j++)
#pragma unroll
      for (int r = 0; r < 4; r++) acc[i][j][r] = 0.f;

  for (int k0 = 0; k0 < K; k0 += TK) {
    // ---- stage A tile: 128 rows x 32 bf16; chunk c = 16B = 8 elems.
    // LDS offset MUST be lane-ordered: chunk c lands at Asm + c*8.
#pragma unroll
    for (int p = 0; p < 2; p++) {
      int c = tid + p * 256;       // 0..511
      int r = c >> 2;              // tile row 0..127
      int koff = (c & 3) * 8;      // 0,8,16,24
      int row = m0 + r;
      if (row >= M) row = M - 1;   // clamp (harmless dup)
      long grow = row_mode ? ((long)(row >> 2) * PP + (row & 3)) : (long)row;
      const __hip_bfloat16* gp = A + grow * lda + k0 + koff;
      __builtin_amdgcn_global_load_lds(
          (const __attribute__((address_space(1))) unsigned int*)gp,
          (__attribute__((address_space(3))) unsigned int*)(&Asm[c * 8]), 16,
          0, 0);
    }
    // ---- stage BT tile: 128 rows (n) x 32 bf16
#pragma unroll
    for (int p = 0; p < 2; p++) {
      int c = tid + p * 256;
      int r = c >> 2;
      int koff = (c & 3) * 8;
      int row = n0 + r;
      if (row >= N) row = N - 1;   // clamp; garbage cols never stored
      const __hip_bfloat16* gp = BT + (long)row * ldbt + k0 + koff;
      __builtin_amdgcn_global_load_lds(
          (const __attribute__((address_space(1))) unsigned int*)gp,
          (__attribute__((address_space(3))) unsigned int*)(&Bsm[c * 8]), 16,
          0, 0);
    }
    __syncthreads();  // drains vmcnt before barrier (compiler-inserted)

    // ---- fragments + 16 MFMAs
    bf16x8v af[4], bf[4];
#pragma unroll
    for (int mi = 0; mi < 4; mi++)
      af[mi] = *(const bf16x8v*)&Asm[(wm + mi * 16 + col_l) * TK + quad * 8];
#pragma unroll
    for (int ni = 0; ni < 4; ni++)
      bf[ni] = *(const bf16x8v*)&Bsm[(wn + ni * 16 + col_l) * TK + quad * 8];
#pragma unroll
    for (int mi = 0; mi < 4; mi++)
#pragma unroll
      for (int ni = 0; ni < 4; ni++)
        acc[mi][ni] = __builtin_amdgcn_mfma_f32_16x16x32_bf16(
            af[mi], bf[ni], acc[mi][ni], 0, 0, 0);
    __syncthreads();
  }

  // ---- epilogue: C/D layout col=lane&15 (N), row=quad*4+reg (M)  [m89]
  const int store_f32 = (c_mode == 1) || (c_mode == 2 && outflag && outflag[0]);
#pragma unroll
  for (int mi = 0; mi < 4; mi++) {
    int rbase = m0 + wm + mi * 16 + quad * 4;
#pragma unroll
    for (int ni = 0; ni < 4; ni++) {
      int col = n0 + wn + ni * 16 + col_l;
      if (col >= N) continue;
      float bv = bias ? __bfloat162float(bias[col]) : 0.f;
#pragma unroll
      for (int r = 0; r < 4; r++) {
        int row = rbase + r;
        if (row >= M) continue;
        float v = acc[mi][ni][r] + bv;
        if (do_relu) v = fmaxf(v, 0.f);
        if (store_f32)
          ((float*)Cout)[(long)row * ldc + col] = v;
        else
          ((__hip_bfloat16*)Cout)[(long)row * ldc + col] = __float2bfloat16(v);
      }
    }
  }
}

// ---------------------------------------------------------------------------
// Per-node attention logits: es[n] = h[n,:].a[0:D], ed[n] = h[n,:].a[D:2D]
// ---------------------------------------------------------------------------
template <int DIM>
__global__ __launch_bounds__(256) void edge_logits(
    const float* __restrict__ h, const __hip_bfloat16* __restrict__ a,
    float* __restrict__ es, float* __restrict__ ed) {
  const int n = blockIdx.x;
  const int t = threadIdx.x;
  float s1 = 0.f, s2 = 0.f;
  for (int f = t; f < DIM; f += 256) {
    float hv = h[(long)n * DIM + f];
    s1 += hv * __bfloat162float(a[f]);
    s2 += hv * __bfloat162float(a[DIM + f]);
  }
#pragma unroll
  for (int off = 32; off > 0; off >>= 1) {
    s1 += __shfl_down(s1, off);
    s2 += __shfl_down(s2, off);
  }
  __shared__ float r1[4], r2[4];
  int lane = t & 63, wid = t >> 6;
  if (lane == 0) { r1[wid] = s1; r2[wid] = s2; }
  __syncthreads();
  if (t == 0) {
    es[n] = r1[0] + r1[1] + r1[2] + r1[3];
    ed[n] = r2[0] + r2[1] + r2[2] + r2[3];
  }
}

// ---------------------------------------------------------------------------
// GAT update per dst node; x/out have leading dim DIMP (zero-padded cols),
// h has leading dim DIM. All barriers wave-uniform.
// ---------------------------------------------------------------------------
template <int DIM, int DIMP>
__global__ __launch_bounds__(256) void attn_update(
    const __hip_bfloat16* __restrict__ x, const float* __restrict__ h,
    const float* __restrict__ es, const float* __restrict__ ed,
    __hip_bfloat16* __restrict__ out) {
  const int n = blockIdx.x;
  const int b = n / PP, d = n % PP;
  const int t = threadIdx.x;
  __shared__ float logit[PP];
  __shared__ float alpha[PP];
  __shared__ float red[2];

  if (t < PP) {
    float e;
    if (t == d) {
      e = -1e30f;                    // self-edge excluded: exp -> 0
    } else {
      float v = es[b * PP + t] + ed[n];
      e = (v > 0.f) ? v : 0.2f * v;  // leaky_relu 0.2
    }
    logit[t] = e;
  }
  __syncthreads();
  if (t == 0) {
    float m = -1e30f;
    for (int s = 0; s < PP; s++) m = fmaxf(m, logit[s]);
    float sum = 0.f;
    for (int s = 0; s < PP; s++) sum += expf(logit[s] - m);
    red[0] = m;
    red[1] = sum;
  }
  __syncthreads();
  if (t < PP) alpha[t] = expf(logit[t] - red[0]) / (red[1] + 1e-9f);
  __syncthreads();

  for (int f = t; f < DIMP; f += 256) {
    float v = 0.f;
    if (f < DIM) {
      float acc = 0.f;
#pragma unroll
      for (int s = 0; s < PP; s++)
        acc += alpha[s] * h[(long)(b * PP + s) * DIM + f];
      v = __bfloat162float(x[(long)n * DIMP + f]) + acc;
      v = v > 0.f ? v : 0.f;
    }
    out[(long)n * DIMP + f] = __float2bfloat16(v);
  }
}

// ---------------------------------------------------------------------------
// Combine per readout edge: hdn[e,:] = relu(Yd_v[hd] + Yd_l[hd] + Ys_v[s] +
//   Ys_l[s] + sf@W1sp + b1), stored bf16.
// ---------------------------------------------------------------------------
__global__ __launch_bounds__(256) void combine_kernel(
    const int* __restrict__ edge_src, const int* __restrict__ edge_dst,
    const int* __restrict__ readout_eid,
    const __hip_bfloat16* __restrict__ spatial,
    const __hip_bfloat16* __restrict__ W1sp,
    const __hip_bfloat16* __restrict__ b1,
    const __hip_bfloat16* __restrict__ Yd_v,
    const __hip_bfloat16* __restrict__ Yd_l,
    const __hip_bfloat16* __restrict__ Ys_v,
    const __hip_bfloat16* __restrict__ Ys_l,
    __hip_bfloat16* __restrict__ hdn) {
  const int e = blockIdx.x;
  const int re = readout_eid[e];
  const int s = edge_src[re];
  const int d = edge_dst[re];
  const int hidx = (d / PP) * HH + (d % PP);
  const int t = threadIdx.x;
  __shared__ float sf[SS];
  if (t < SS) sf[t] = __bfloat162float(spatial[(long)re * SS + t]);
  __syncthreads();
  for (int hd = t; hd < HDIM; hd += 256) {
    float v = __bfloat162float(Yd_v[(long)hidx * HDIM + hd]) +
              __bfloat162float(Yd_l[(long)hidx * HDIM + hd]) +
              __bfloat162float(Ys_v[(long)s * HDIM + hd]) +
              __bfloat162float(Ys_l[(long)s * HDIM + hd]) +
              __bfloat162float(b1[hd]);
#pragma unroll
    for (int k = 0; k < SS; k++)
      v += sf[k] * __bfloat162float(W1sp[(long)k * HDIM + hd]);
    hdn[(long)e * HDIM + hd] = __float2bfloat16(v > 0.f ? v : 0.f);
  }
}

// ---------------------------------------------------------------------------
extern "C" void kernel_launch(void* const* d_in, const int* in_sizes, int n_in,
                              void* d_out, int out_size, void* d_ws,
                              size_t ws_size, hipStream_t stream) {
  const int* e_src = (const int*)d_in[11];
  const int* e_dst = (const int*)d_in[12];
  const int* r_eid = (const int*)d_in[13];
  (void)ws_size; (void)n_in; (void)in_sizes; (void)out_size;

  char* ws = (char*)d_ws;
  size_t off = 0;
  auto take = [&](size_t bytes) {
    char* p = ws + off;
    off += (bytes + 255) & ~(size_t)255;
    return p;
  };

  int* dflag = (int*)take(256);
  // canonical bf16 inputs (A-side + small vectors)
  __hip_bfloat16* cF   = (__hip_bfloat16*)take((size_t)NNODE * FF * 2);
  __hip_bfloat16* cLp  = (__hip_bfloat16*)take((size_t)NNODE * LLP * 2);
  __hip_bfloat16* cSp  = (__hip_bfloat16*)take((size_t)BB * PP * (PP - 1) * SS * 2);
  __hip_bfloat16* cAv  = (__hip_bfloat16*)take((size_t)2 * FF * 2);
  __hip_bfloat16* cAl  = (__hip_bfloat16*)take((size_t)2 * LL * 2);
  __hip_bfloat16* cB1  = (__hip_bfloat16*)take((size_t)HDIM * 2);
  __hip_bfloat16* cB2  = (__hip_bfloat16*)take((size_t)CC * 2);
  __hip_bfloat16* cW1sp = (__hip_bfloat16*)take((size_t)SS * HDIM * 2);
  // transposed (B^T) weights, K zero-padded to multiples of 32
  __hip_bfloat16* WvT   = (__hip_bfloat16*)take((size_t)FF * FF * 2);
  __hip_bfloat16* WlT   = (__hip_bfloat16*)take((size_t)LL * LLP * 2);
  __hip_bfloat16* W1Tdv = (__hip_bfloat16*)take((size_t)HDIM * FF * 2);
  __hip_bfloat16* W1Tdl = (__hip_bfloat16*)take((size_t)HDIM * LLP * 2);
  __hip_bfloat16* W1Tsl = (__hip_bfloat16*)take((size_t)HDIM * LLP * 2);
  __hip_bfloat16* W1Tsv = (__hip_bfloat16*)take((size_t)HDIM * FF * 2);
  __hip_bfloat16* W2T   = (__hip_bfloat16*)take((size_t)CC * HDIM * 2);

  // seg1 overlay: phase A = h_v/h_l (fp32) + logits; phase B = Y arrays (bf16)
  const size_t PHASE_A = (size_t)NNODE * FF * 4 + (size_t)NNODE * LL * 4 +
                         4 * ((size_t)NNODE * 4 + 256);
  char* seg1 = take(PHASE_A);
  float* h_v = (float*)seg1;
  float* h_l = (float*)(seg1 + (size_t)NNODE * FF * 4);
  float* es_v = (float*)(seg1 + (size_t)NNODE * FF * 4 + (size_t)NNODE * LL * 4);
  float* ed_v = es_v + NNODE + 64;
  float* es_l = ed_v + NNODE + 64;
  float* ed_l = es_l + NNODE + 64;
  __hip_bfloat16* Yd_v = (__hip_bfloat16*)seg1;  // phase B overlay
  __hip_bfloat16* Yd_l = Yd_v + (size_t)BB * HH * HDIM;
  __hip_bfloat16* Ys_v = Yd_l + (size_t)BB * HH * HDIM;
  __hip_bfloat16* Ys_l = Ys_v + (size_t)NNODE * HDIM;

  __hip_bfloat16* new_f = (__hip_bfloat16*)take((size_t)NNODE * FF * 2);
  __hip_bfloat16* new_lp = (__hip_bfloat16*)take((size_t)NNODE * LLP * 2);
  __hip_bfloat16* hdn = (__hip_bfloat16*)take((size_t)NREAD * HDIM * 2);

  dim3 blk(256);

  // 0) sniff dtype
  sniff_dtype<<<1, blk, 0, stream>>>((const unsigned short*)d_in[0], dflag);

  // 0b) canonicalize flat inputs
  auto conv = [&](int idx, __hip_bfloat16* dst, long row0, int R, int C,
                  int ld, int Cp) {
    long total = (long)R * Cp;
    convert_pad<<<(int)((total + 255) / 256), blk, 0, stream>>>(
        d_in[idx], dst, row0, R, C, ld, Cp, dflag);
  };
  conv(0, cF, 0, NNODE, FF, FF, FF);
  conv(1, cLp, 0, NNODE, LL, LL, LLP);
  conv(2, cSp, 0, BB * PP * (PP - 1), SS, SS, SS);
  conv(4, cAv, 0, 1, 2 * FF, 2 * FF, 2 * FF);
  conv(6, cAl, 0, 1, 2 * LL, 2 * LL, 2 * LL);
  conv(8, cB1, 0, 1, HDIM, HDIM, HDIM);
  conv(10, cB2, 0, 1, CC, CC, CC);
  conv(7, cW1sp, 1324, SS, HDIM, HDIM, HDIM);

  // 0c) transposed weights (B^T, K-padded)
  auto convT = [&](int idx, __hip_bfloat16* dst, long row0, int K, int N,
                   int ld, int Kp) {
    dim3 grid((Kp + 31) / 32, (N + 31) / 32);
    convert_transpose<<<grid, blk, 0, stream>>>(d_in[idx], dst, row0, K, N, ld,
                                                Kp, dflag);
  };
  convT(3, WvT, 0, FF, FF, FF, FF);
  convT(5, WlT, 0, LL, LL, LL, LLP);
  convT(7, W1Tdv, 0, FF, HDIM, HDIM, FF);
  convT(7, W1Tdl, 1024, LL, HDIM, HDIM, LLP);
  convT(7, W1Tsl, 1340, LL, HDIM, HDIM, LLP);
  convT(7, W1Tsv, 1640, FF, HDIM, HDIM, FF);
  convT(9, W2T, 0, HDIM, CC, CC, HDIM);

  auto gemm = [&](const __hip_bfloat16* A, const __hip_bfloat16* BT, void* C,
                  const __hip_bfloat16* bias, int M, int N, int K, int lda,
                  int ldbt, int ldc, int row_mode, int relu, int c_mode,
                  const int* oflag) {
    dim3 grid((N + TN - 1) / TN, (M + TM - 1) / TM);
    gemm_mfma_bt<<<grid, blk, 0, stream>>>(A, BT, C, bias, M, N, K, lda, ldbt,
                                           ldc, row_mode, relu, c_mode, oflag);
  };

  // 1) Projections h = x @ W (fp32 out)
  gemm(cF, WvT, h_v, nullptr, NNODE, FF, FF, FF, FF, FF, 0, 0, 1, nullptr);
  gemm(cLp, WlT, h_l, nullptr, NNODE, LL, LLP, LLP, LLP, LL, 0, 0, 1, nullptr);

  // 2) Attention logits
  edge_logits<FF><<<NNODE, blk, 0, stream>>>(h_v, cAv, es_v, ed_v);
  edge_logits<LL><<<NNODE, blk, 0, stream>>>(h_l, cAl, es_l, ed_l);

  // 3) GAT update
  attn_update<FF, FF><<<NNODE, blk, 0, stream>>>(cF, h_v, es_v, ed_v, new_f);
  attn_update<LL, LLP><<<NNODE, blk, 0, stream>>>(cLp, h_l, es_l, ed_l, new_lp);

  // 4) Decomposed x@W1 per-node projections (bf16 out, overlays phase A)
  gemm(new_f, W1Tdv, Yd_v, nullptr, BB * HH, HDIM, FF, FF, FF, HDIM, 1, 0, 0,
       nullptr);
  gemm(new_lp, W1Tdl, Yd_l, nullptr, BB * HH, HDIM, LLP, LLP, LLP, HDIM, 1, 0,
       0, nullptr);
  gemm(new_lp, W1Tsl, Ys_l, nullptr, NNODE, HDIM, LLP, LLP, LLP, HDIM, 0, 0, 0,
       nullptr);
  gemm(new_f, W1Tsv, Ys_v, nullptr, NNODE, HDIM, FF, FF, FF, HDIM, 0, 0, 0,
       nullptr);

  // 5) Combine + relu -> hdn (bf16)
  combine_kernel<<<NREAD, blk, 0, stream>>>(e_src, e_dst, r_eid, cSp, cW1sp,
                                            cB1, Yd_v, Yd_l, Ys_v, Ys_l, hdn);

  // 6) out = hdn @ W2 + b2; output dtype per sniffed flag
  gemm(hdn, W2T, d_out, cB2, NREAD, CC, HDIM, HDIM, HDIM, CC, 0, 0, 2, dflag);
}

// Round 5
// 362.722 us; speedup vs baseline: 2.8980x; 1.2053x over previous
//
#include <hip/hip_runtime.h>
#include <hip/hip_bf16.h>

// Problem constants
#define BB 256
#define PP 20
#define HH 4
#define FF 1024
#define LL 300
#define LLP 320   // LL padded to multiple of 32 for MFMA K-loop
#define SS 16
#define HDIM 1024
#define CC 117
#define NNODE (BB * PP)              // 5120
#define NREAD (BB * (PP * HH - HH))  // 19456
#define EPB 8                        // edges per combine block

typedef __attribute__((ext_vector_type(8))) short bf16x8v;  // 8 bf16 = 4 VGPRs
typedef __attribute__((ext_vector_type(4))) float f32x4v;
typedef __attribute__((ext_vector_type(4))) unsigned short u16x4;

__device__ __forceinline__ float bf2f(unsigned short u) {
  return __uint_as_float((unsigned int)u << 16);
}
__device__ __forceinline__ unsigned short f2b(float f) {
  __hip_bfloat16 h = __float2bfloat16(f);
  return *(unsigned short*)&h;
}

// ---------------------------------------------------------------------------
// Dtype sniff: bf16 N(0,1) data -> ~512/512 magnitudes in [2^-30,2^30];
// fp32 read as bf16 -> only ~61%. flag[0]=1 means "inputs are fp32".
// ---------------------------------------------------------------------------
__global__ void sniff_dtype(const unsigned short* __restrict__ buf,
                            int* __restrict__ flag) {
  int t = threadIdx.x;
  int votes = 0;
  for (int i = t; i < 512; i += 256) {
    unsigned int u = (unsigned int)buf[i] << 16;
    float v = __uint_as_float(u);
    float a = fabsf(v);
    if (v == v && a > 9.3e-10f && a < 1.1e9f) votes++;
  }
  __shared__ int sv[256];
  sv[t] = votes;
  __syncthreads();
  for (int s = 128; s > 0; s >>= 1) {
    if (t < s) sv[t] += sv[t + s];
    __syncthreads();
  }
  if (t == 0) flag[0] = (sv[0] < 448) ? 1 : 0;
}

// ---------------------------------------------------------------------------
// Flat vectorized convert (no padding): n4 groups of 4 elements.
// bf16 case degenerates to an 8-byte copy.
// ---------------------------------------------------------------------------
__global__ __launch_bounds__(256) void convert_flat4(
    const void* __restrict__ src, __hip_bfloat16* __restrict__ dst, long n4,
    const int* __restrict__ flag) {
  long i = (long)blockIdx.x * 256 + threadIdx.x;
  if (i >= n4) return;
  if (flag[0]) {
    float4 v = ((const float4*)src)[i];
    u16x4 o;
    o[0] = f2b(v.x); o[1] = f2b(v.y); o[2] = f2b(v.z); o[3] = f2b(v.w);
    *(u16x4*)(dst + i * 4) = o;
  } else {
    ((unsigned long long*)dst)[i] = ((const unsigned long long*)src)[i];
  }
}

// ---------------------------------------------------------------------------
// Padded convert (scalar): dst[R x Cp] from src[R x C] (ld), zero col-pad.
// ---------------------------------------------------------------------------
__global__ __launch_bounds__(256) void convert_pad(
    const void* __restrict__ src, __hip_bfloat16* __restrict__ dst, long row0,
    int R, int C, int ld, int Cp, const int* __restrict__ flag) {
  long i = (long)blockIdx.x * 256 + threadIdx.x;
  long total = (long)R * Cp;
  if (i >= total) return;
  int r = (int)(i / Cp), c = (int)(i % Cp);
  float v = 0.f;
  if (c < C) {
    long idx = (row0 + r) * (long)ld + c;
    v = flag[0] ? ((const float*)src)[idx]
                : __bfloat162float(((const __hip_bfloat16*)src)[idx]);
  }
  dst[i] = __float2bfloat16(v);
}

// ---------------------------------------------------------------------------
// All small flat converts in one launch: cAv(2048) cAl(600) cB1(1024)
// cB2(117) cW1sp(16x1024, W1 rows 1324..1340 = contiguous @ 1355776).
// ---------------------------------------------------------------------------
__global__ __launch_bounds__(256) void convert_smalls(
    const void* __restrict__ s4, const void* __restrict__ s6,
    const void* __restrict__ s7, const void* __restrict__ s8,
    const void* __restrict__ s10, __hip_bfloat16* __restrict__ cAv,
    __hip_bfloat16* __restrict__ cAl, __hip_bfloat16* __restrict__ cB1,
    __hip_bfloat16* __restrict__ cB2, __hip_bfloat16* __restrict__ cW1sp,
    const int* __restrict__ flag) {
  int i = blockIdx.x * 256 + threadIdx.x;
  const int f = flag[0];
  auto rd = [&](const void* p, long idx) -> float {
    return f ? ((const float*)p)[idx]
             : __bfloat162float(((const __hip_bfloat16*)p)[idx]);
  };
  if (i < 2048) cAv[i] = __float2bfloat16(rd(s4, i));
  else if (i < 2648) cAl[i - 2048] = __float2bfloat16(rd(s6, i - 2048));
  else if (i < 3672) cB1[i - 2648] = __float2bfloat16(rd(s8, i - 2648));
  else if (i < 3789) cB2[i - 3672] = __float2bfloat16(rd(s10, i - 3672));
  else if (i < 20173)
    cW1sp[i - 3789] = __float2bfloat16(rd(s7, 1355776L + (i - 3789)));
}

// ---------------------------------------------------------------------------
// All 7 weight transposes in one launch (blockIdx.z descriptor).
// dst[N x Kp] = src[row0..row0+K) x N cols (ld), K zero-padded to Kp.
// ---------------------------------------------------------------------------
__global__ __launch_bounds__(256) void transpose_all(
    const void* __restrict__ s3, const void* __restrict__ s5,
    const void* __restrict__ s7, const void* __restrict__ s9,
    __hip_bfloat16* __restrict__ d0, __hip_bfloat16* __restrict__ d1,
    __hip_bfloat16* __restrict__ d2, __hip_bfloat16* __restrict__ d3,
    __hip_bfloat16* __restrict__ d4, __hip_bfloat16* __restrict__ d5,
    __hip_bfloat16* __restrict__ d6, const int* __restrict__ flag) {
  const int z = blockIdx.z;
  const int ROW0[7] = {0, 0, 0, 1024, 1340, 1640, 0};
  const int KK[7] = {1024, 300, 1024, 300, 300, 1024, 1024};
  const int NN[7] = {1024, 300, 1024, 1024, 1024, 1024, 117};
  const int LD[7] = {1024, 300, 1024, 1024, 1024, 1024, 117};
  const int KP[7] = {1024, 320, 1024, 320, 320, 1024, 1024};
  const void* src = (z == 0) ? s3 : (z == 1) ? s5 : (z == 6) ? s9 : s7;
  __hip_bfloat16* dst = (z == 0) ? d0 : (z == 1) ? d1 : (z == 2) ? d2
                        : (z == 3) ? d3 : (z == 4) ? d4 : (z == 5) ? d5 : d6;
  const int row0 = ROW0[z], K = KK[z], N = NN[z], ld = LD[z], Kp = KP[z];
  const int kb = blockIdx.x * 32, nb = blockIdx.y * 32;
  if (kb >= Kp || nb >= N) return;
  __shared__ float tile[32][33];
  const int tx = threadIdx.x & 31, ty = threadIdx.x >> 5;
  const int fl = flag[0];
  for (int i = ty; i < 32; i += 8) {
    int k = kb + i, n = nb + tx;
    float v = 0.f;
    if (k < K && n < N) {
      long idx = (long)(row0 + k) * ld + n;
      v = fl ? ((const float*)src)[idx]
             : __bfloat162float(((const __hip_bfloat16*)src)[idx]);
    }
    tile[i][tx] = v;
  }
  __syncthreads();
  for (int i = ty; i < 32; i += 8) {
    int n = nb + i, k = kb + tx;
    if (n < N && k < Kp) dst[(long)n * Kp + k] = __float2bfloat16(tile[tx][i]);
  }
}

// ---------------------------------------------------------------------------
// MFMA GEMM (m97 structure): C[M,N] = A[M,K] @ B[K,N], B given as BT[N,K].
// 128x128 tile, BK=32, 4 waves x (4x4 grid of 16x16x32 bf16 MFMA).
// global_load_lds width=16, lane-ordered LDS (no padding — m104).
// row_mode=1 gathers A rows: r -> (r>>2)*PP + (r&3).
// c_mode: 0 bf16 store, 1 fp32 store, 2 branch on outflag[0] (1->fp32).
// ---------------------------------------------------------------------------
#define TM 128
#define TN 128
#define TK 32

__global__ __launch_bounds__(256) void gemm_mfma_bt(
    const __hip_bfloat16* __restrict__ A, const __hip_bfloat16* __restrict__ BT,
    void* __restrict__ Cout, const __hip_bfloat16* __restrict__ bias, int M,
    int N, int K, int lda, int ldbt, int ldc, int row_mode, int do_relu,
    int c_mode, const int* __restrict__ outflag) {
  __shared__ __hip_bfloat16 Asm[TM * TK];
  __shared__ __hip_bfloat16 Bsm[TN * TK];
  const int tid = threadIdx.x;
  const int lane = tid & 63;
  const int wave = tid >> 6;
  const int wm = (wave & 1) * 64;
  const int wn = (wave >> 1) * 64;
  const int m0 = blockIdx.y * TM;
  const int n0 = blockIdx.x * TN;
  const int col_l = lane & 15;
  const int quad = lane >> 4;

  f32x4v acc[4][4];
#pragma unroll
  for (int i = 0; i < 4; i++)
#pragma unroll
    for (int j = 0; j < 4; j++)
#pragma unroll
      for (int r = 0; r < 4; r++) acc[i][j][r] = 0.f;

  for (int k0 = 0; k0 < K; k0 += TK) {
#pragma unroll
    for (int p = 0; p < 2; p++) {
      int c = tid + p * 256;
      int r = c >> 2;
      int koff = (c & 3) * 8;
      int row = m0 + r;
      if (row >= M) row = M - 1;
      long grow = row_mode ? ((long)(row >> 2) * PP + (row & 3)) : (long)row;
      const __hip_bfloat16* gp = A + grow * lda + k0 + koff;
      __builtin_amdgcn_global_load_lds(
          (const __attribute__((address_space(1))) unsigned int*)gp,
          (__attribute__((address_space(3))) unsigned int*)(&Asm[c * 8]), 16,
          0, 0);
    }
#pragma unroll
    for (int p = 0; p < 2; p++) {
      int c = tid + p * 256;
      int r = c >> 2;
      int koff = (c & 3) * 8;
      int row = n0 + r;
      if (row >= N) row = N - 1;
      const __hip_bfloat16* gp = BT + (long)row * ldbt + k0 + koff;
      __builtin_amdgcn_global_load_lds(
          (const __attribute__((address_space(1))) unsigned int*)gp,
          (__attribute__((address_space(3))) unsigned int*)(&Bsm[c * 8]), 16,
          0, 0);
    }
    __syncthreads();

    bf16x8v af[4], bf[4];
#pragma unroll
    for (int mi = 0; mi < 4; mi++)
      af[mi] = *(const bf16x8v*)&Asm[(wm + mi * 16 + col_l) * TK + quad * 8];
#pragma unroll
    for (int ni = 0; ni < 4; ni++)
      bf[ni] = *(const bf16x8v*)&Bsm[(wn + ni * 16 + col_l) * TK + quad * 8];
#pragma unroll
    for (int mi = 0; mi < 4; mi++)
#pragma unroll
      for (int ni = 0; ni < 4; ni++)
        acc[mi][ni] = __builtin_amdgcn_mfma_f32_16x16x32_bf16(
            af[mi], bf[ni], acc[mi][ni], 0, 0, 0);
    __syncthreads();
  }

  const int store_f32 = (c_mode == 1) || (c_mode == 2 && outflag && outflag[0]);
#pragma unroll
  for (int mi = 0; mi < 4; mi++) {
    int rbase = m0 + wm + mi * 16 + quad * 4;
#pragma unroll
    for (int ni = 0; ni < 4; ni++) {
      int col = n0 + wn + ni * 16 + col_l;
      if (col >= N) continue;
      float bv = bias ? __bfloat162float(bias[col]) : 0.f;
#pragma unroll
      for (int r = 0; r < 4; r++) {
        int row = rbase + r;
        if (row >= M) continue;
        float v = acc[mi][ni][r] + bv;
        if (do_relu) v = fmaxf(v, 0.f);
        if (store_f32)
          ((float*)Cout)[(long)row * ldc + col] = v;
        else
          ((__hip_bfloat16*)Cout)[(long)row * ldc + col] = __float2bfloat16(v);
      }
    }
  }
}

// ---------------------------------------------------------------------------
// Attention logits (h bf16, stride HLD): es[n]=h.a[0:D], ed[n]=h.a[D:2D]
// ---------------------------------------------------------------------------
template <int DIM, int HLD>
__global__ __launch_bounds__(256) void edge_logits(
    const __hip_bfloat16* __restrict__ h, const __hip_bfloat16* __restrict__ a,
    float* __restrict__ es, float* __restrict__ ed) {
  const int n = blockIdx.x;
  const int t = threadIdx.x;
  constexpr int CH = DIM / 4;  // DIM % 4 == 0 (256 or 75 chunks)
  float s1 = 0.f, s2 = 0.f;
  for (int c = t; c < CH; c += 256) {
    int f = c * 4;
    u16x4 hv = *(const u16x4*)(h + (long)n * HLD + f);
    u16x4 av = *(const u16x4*)(a + f);
    u16x4 dv = *(const u16x4*)(a + DIM + f);
#pragma unroll
    for (int j = 0; j < 4; j++) {
      float hf = bf2f(hv[j]);
      s1 += hf * bf2f(av[j]);
      s2 += hf * bf2f(dv[j]);
    }
  }
#pragma unroll
  for (int off = 32; off > 0; off >>= 1) {
    s1 += __shfl_down(s1, off);
    s2 += __shfl_down(s2, off);
  }
  __shared__ float r1[4], r2[4];
  int lane = t & 63, wid = t >> 6;
  if (lane == 0) { r1[wid] = s1; r2[wid] = s2; }
  __syncthreads();
  if (t == 0) {
    es[n] = r1[0] + r1[1] + r1[2] + r1[3];
    ed[n] = r2[0] + r2[1] + r2[2] + r2[3];
  }
}

// ---------------------------------------------------------------------------
// GAT update per dst node (h bf16 stride HLD, x/out stride DIMP, zero-pad).
// All barriers wave-uniform.
// ---------------------------------------------------------------------------
template <int DIM, int DIMP, int HLD>
__global__ __launch_bounds__(256) void attn_update(
    const __hip_bfloat16* __restrict__ x, const __hip_bfloat16* __restrict__ h,
    const float* __restrict__ es, const float* __restrict__ ed,
    __hip_bfloat16* __restrict__ out) {
  const int n = blockIdx.x;
  const int b = n / PP, d = n % PP;
  const int t = threadIdx.x;
  __shared__ float logit[PP];
  __shared__ float alpha[PP];
  __shared__ float red[2];

  if (t < PP) {
    float e;
    if (t == d) {
      e = -1e30f;
    } else {
      float v = es[b * PP + t] + ed[n];
      e = (v > 0.f) ? v : 0.2f * v;  // leaky_relu 0.2
    }
    logit[t] = e;
  }
  __syncthreads();
  if (t == 0) {
    float m = -1e30f;
    for (int s = 0; s < PP; s++) m = fmaxf(m, logit[s]);
    float sum = 0.f;
    for (int s = 0; s < PP; s++) sum += expf(logit[s] - m);
    red[0] = m;
    red[1] = sum;
  }
  __syncthreads();
  if (t < PP) alpha[t] = expf(logit[t] - red[0]) / (red[1] + 1e-9f);
  __syncthreads();

  constexpr int CH = DIMP / 4;
  const long hbase = (long)b * PP * HLD;
  for (int c = t; c < CH; c += 256) {
    int f = c * 4;
    u16x4 ov;
    if (f < DIM) {  // DIM % 4 == 0: chunk fully in-range
      float a0 = 0.f, a1 = 0.f, a2 = 0.f, a3 = 0.f;
#pragma unroll
      for (int s = 0; s < PP; s++) {
        u16x4 hv = *(const u16x4*)(h + hbase + (long)s * HLD + f);
        float al = alpha[s];
        a0 += al * bf2f(hv[0]);
        a1 += al * bf2f(hv[1]);
        a2 += al * bf2f(hv[2]);
        a3 += al * bf2f(hv[3]);
      }
      u16x4 xv = *(const u16x4*)(x + (long)n * DIMP + f);
      float v0 = fmaxf(bf2f(xv[0]) + a0, 0.f);
      float v1 = fmaxf(bf2f(xv[1]) + a1, 0.f);
      float v2 = fmaxf(bf2f(xv[2]) + a2, 0.f);
      float v3 = fmaxf(bf2f(xv[3]) + a3, 0.f);
      ov[0] = f2b(v0); ov[1] = f2b(v1); ov[2] = f2b(v2); ov[3] = f2b(v3);
    } else {
      ov[0] = 0; ov[1] = 0; ov[2] = 0; ov[3] = 0;
    }
    *(u16x4*)(out + (long)n * DIMP + f) = ov;
  }
}

// ---------------------------------------------------------------------------
// Combine, 8 edges/block, vectorized. Thread t owns hd slice [4t, 4t+4).
// W1sp column slice + bias cached in registers across the 8 edges.
// Spatial read straight from the raw input (flag-branched dtype).
// ---------------------------------------------------------------------------
__global__ __launch_bounds__(256) void combine_kernel(
    const int* __restrict__ e_src, const int* __restrict__ e_dst,
    const int* __restrict__ r_eid, const void* __restrict__ spat_raw,
    const __hip_bfloat16* __restrict__ W1sp,
    const __hip_bfloat16* __restrict__ b1,
    const __hip_bfloat16* __restrict__ Yd_v,
    const __hip_bfloat16* __restrict__ Yd_l,
    const __hip_bfloat16* __restrict__ Ys_v,
    const __hip_bfloat16* __restrict__ Ys_l,
    __hip_bfloat16* __restrict__ hdn, const int* __restrict__ flag) {
  const int t = threadIdx.x;
  const int e0 = blockIdx.x * EPB;
  const int hd = t * 4;  // 256 threads x 4 = HDIM exactly

  // Per-thread W1sp column slice (16 x 4) + bias, reused across EPB edges.
  float w[SS][4];
#pragma unroll
  for (int k = 0; k < SS; k++) {
    u16x4 ww = *(const u16x4*)(W1sp + (long)k * HDIM + hd);
#pragma unroll
    for (int j = 0; j < 4; j++) w[k][j] = bf2f(ww[j]);
  }
  float bb[4];
  {
    u16x4 bv = *(const u16x4*)(b1 + hd);
#pragma unroll
    for (int j = 0; j < 4; j++) bb[j] = bf2f(bv[j]);
  }

  __shared__ int sh_s[EPB], sh_hx[EPB], sh_re[EPB];
  __shared__ float sh_sf[EPB][SS];
  if (t < EPB) {
    int re = r_eid[e0 + t];
    sh_re[t] = re;
    sh_s[t] = e_src[re];
    int d = e_dst[re];
    sh_hx[t] = (d / PP) * HH + (d % PP);
  }
  __syncthreads();
  if (t < EPB * SS) {
    int ee = t >> 4, k = t & 15;
    long idx = (long)sh_re[ee] * SS + k;
    sh_sf[ee][k] = flag[0]
                       ? ((const float*)spat_raw)[idx]
                       : __bfloat162float(((const __hip_bfloat16*)spat_raw)[idx]);
  }
  __syncthreads();

#pragma unroll
  for (int ee = 0; ee < EPB; ee++) {
    const int s = sh_s[ee];
    const int hx = sh_hx[ee];
    u16x4 ydv = *(const u16x4*)(Yd_v + (long)hx * HDIM + hd);
    u16x4 ydl = *(const u16x4*)(Yd_l + (long)hx * HDIM + hd);
    u16x4 ysv = *(const u16x4*)(Ys_v + (long)s * HDIM + hd);
    u16x4 ysl = *(const u16x4*)(Ys_l + (long)s * HDIM + hd);
    float v[4];
#pragma unroll
    for (int j = 0; j < 4; j++)
      v[j] = bf2f(ydv[j]) + bf2f(ydl[j]) + bf2f(ysv[j]) + bf2f(ysl[j]) + bb[j];
#pragma unroll
    for (int k = 0; k < SS; k++) {
      float sfv = sh_sf[ee][k];
#pragma unroll
      for (int j = 0; j < 4; j++) v[j] += sfv * w[k][j];
    }
    u16x4 o;
#pragma unroll
    for (int j = 0; j < 4; j++) o[j] = f2b(fmaxf(v[j], 0.f));
    *(u16x4*)(hdn + (long)(e0 + ee) * HDIM + hd) = o;
  }
}

// ---------------------------------------------------------------------------
extern "C" void kernel_launch(void* const* d_in, const int* in_sizes, int n_in,
                              void* d_out, int out_size, void* d_ws,
                              size_t ws_size, hipStream_t stream) {
  const int* e_src = (const int*)d_in[11];
  const int* e_dst = (const int*)d_in[12];
  const int* r_eid = (const int*)d_in[13];
  (void)ws_size; (void)n_in; (void)in_sizes; (void)out_size;

  char* ws = (char*)d_ws;
  size_t off = 0;
  auto take = [&](size_t bytes) {
    char* p = ws + off;
    off += (bytes + 255) & ~(size_t)255;
    return p;
  };

  int* dflag = (int*)take(256);
  __hip_bfloat16* cF   = (__hip_bfloat16*)take((size_t)NNODE * FF * 2);
  __hip_bfloat16* cLp  = (__hip_bfloat16*)take((size_t)NNODE * LLP * 2);
  __hip_bfloat16* cAv  = (__hip_bfloat16*)take((size_t)2 * FF * 2);
  __hip_bfloat16* cAl  = (__hip_bfloat16*)take((size_t)2 * LL * 2);
  __hip_bfloat16* cB1  = (__hip_bfloat16*)take((size_t)HDIM * 2);
  __hip_bfloat16* cB2  = (__hip_bfloat16*)take((size_t)CC * 2);
  __hip_bfloat16* cW1sp = (__hip_bfloat16*)take((size_t)SS * HDIM * 2);
  __hip_bfloat16* WvT   = (__hip_bfloat16*)take((size_t)FF * FF * 2);
  __hip_bfloat16* WlT   = (__hip_bfloat16*)take((size_t)LL * LLP * 2);
  __hip_bfloat16* W1Tdv = (__hip_bfloat16*)take((size_t)HDIM * FF * 2);
  __hip_bfloat16* W1Tdl = (__hip_bfloat16*)take((size_t)HDIM * LLP * 2);
  __hip_bfloat16* W1Tsl = (__hip_bfloat16*)take((size_t)HDIM * LLP * 2);
  __hip_bfloat16* W1Tsv = (__hip_bfloat16*)take((size_t)HDIM * FF * 2);
  __hip_bfloat16* W2T   = (__hip_bfloat16*)take((size_t)CC * HDIM * 2);

  // seg1 overlay: phase A = h_v/h_l (bf16) + logits; phase B = Y arrays (bf16)
  const size_t PH_A = (size_t)NNODE * FF * 2 + (size_t)NNODE * LLP * 2 +
                      4 * ((size_t)NNODE * 4 + 256);
  const size_t PH_B = 2 * (size_t)BB * HH * HDIM * 2 + 2 * (size_t)NNODE * HDIM * 2;
  char* seg1 = take(PH_A > PH_B ? PH_A : PH_B);
  __hip_bfloat16* h_v = (__hip_bfloat16*)seg1;
  __hip_bfloat16* h_l = (__hip_bfloat16*)(seg1 + (size_t)NNODE * FF * 2);
  float* es_v = (float*)(seg1 + (size_t)NNODE * FF * 2 + (size_t)NNODE * LLP * 2);
  float* ed_v = es_v + NNODE + 64;
  float* es_l = ed_v + NNODE + 64;
  float* ed_l = es_l + NNODE + 64;
  __hip_bfloat16* Yd_v = (__hip_bfloat16*)seg1;  // phase B overlay
  __hip_bfloat16* Yd_l = Yd_v + (size_t)BB * HH * HDIM;
  __hip_bfloat16* Ys_v = Yd_l + (size_t)BB * HH * HDIM;
  __hip_bfloat16* Ys_l = Ys_v + (size_t)NNODE * HDIM;

  __hip_bfloat16* new_f = (__hip_bfloat16*)take((size_t)NNODE * FF * 2);
  __hip_bfloat16* new_lp = (__hip_bfloat16*)take((size_t)NNODE * LLP * 2);
  __hip_bfloat16* hdn = (__hip_bfloat16*)take((size_t)NREAD * HDIM * 2);

  dim3 blk(256);

  // 0) sniff dtype
  sniff_dtype<<<1, blk, 0, stream>>>((const unsigned short*)d_in[0], dflag);

  // 0b) canonicalize inputs
  {
    long n4 = (long)NNODE * FF / 4;
    convert_flat4<<<(int)((n4 + 255) / 256), blk, 0, stream>>>(d_in[0], cF, n4,
                                                               dflag);
  }
  {
    long total = (long)NNODE * LLP;
    convert_pad<<<(int)((total + 255) / 256), blk, 0, stream>>>(
        d_in[1], cLp, 0, NNODE, LL, LL, LLP, dflag);
  }
  convert_smalls<<<79, blk, 0, stream>>>(d_in[4], d_in[6], d_in[7], d_in[8],
                                         d_in[10], cAv, cAl, cB1, cB2, cW1sp,
                                         dflag);
  // 0c) all weight transposes (one launch)
  {
    dim3 grid(32, 32, 7);
    transpose_all<<<grid, blk, 0, stream>>>(d_in[3], d_in[5], d_in[7], d_in[9],
                                            WvT, WlT, W1Tdv, W1Tdl, W1Tsl,
                                            W1Tsv, W2T, dflag);
  }

  auto gemm = [&](const __hip_bfloat16* A, const __hip_bfloat16* BT, void* C,
                  const __hip_bfloat16* bias, int M, int N, int K, int lda,
                  int ldbt, int ldc, int row_mode, int relu, int c_mode,
                  const int* oflag) {
    dim3 grid((N + TN - 1) / TN, (M + TM - 1) / TM);
    gemm_mfma_bt<<<grid, blk, 0, stream>>>(A, BT, C, bias, M, N, K, lda, ldbt,
                                           ldc, row_mode, relu, c_mode, oflag);
  };

  // 1) Projections h = x @ W (bf16 out)
  gemm(cF, WvT, h_v, nullptr, NNODE, FF, FF, FF, FF, FF, 0, 0, 0, nullptr);
  gemm(cLp, WlT, h_l, nullptr, NNODE, LL, LLP, LLP, LLP, LLP, 0, 0, 0, nullptr);

  // 2) Attention logits
  edge_logits<FF, FF><<<NNODE, blk, 0, stream>>>(h_v, cAv, es_v, ed_v);
  edge_logits<LL, LLP><<<NNODE, blk, 0, stream>>>(h_l, cAl, es_l, ed_l);

  // 3) GAT update
  attn_update<FF, FF, FF><<<NNODE, blk, 0, stream>>>(cF, h_v, es_v, ed_v,
                                                     new_f);
  attn_update<LL, LLP, LLP><<<NNODE, blk, 0, stream>>>(cLp, h_l, es_l, ed_l,
                                                       new_lp);

  // 4) Decomposed x@W1 per-node projections (bf16 out, overlays phase A)
  gemm(new_f, W1Tdv, Yd_v, nullptr, BB * HH, HDIM, FF, FF, FF, HDIM, 1, 0, 0,
       nullptr);
  gemm(new_lp, W1Tdl, Yd_l, nullptr, BB * HH, HDIM, LLP, LLP, LLP, HDIM, 1, 0,
       0, nullptr);
  gemm(new_lp, W1Tsl, Ys_l, nullptr, NNODE, HDIM, LLP, LLP, LLP, HDIM, 0, 0, 0,
       nullptr);
  gemm(new_f, W1Tsv, Ys_v, nullptr, NNODE, HDIM, FF, FF, FF, HDIM, 0, 0, 0,
       nullptr);

  // 5) Combine + relu -> hdn (bf16), spatial read raw (dtype-branched)
  combine_kernel<<<NREAD / EPB, blk, 0, stream>>>(e_src, e_dst, r_eid, d_in[2],
                                                  cW1sp, cB1, Yd_v, Yd_l, Ys_v,
                                                  Ys_l, hdn, dflag);

  // 6) out = hdn @ W2 + b2; output dtype per sniffed flag
  gemm(hdn, W2T, d_out, cB2, NREAD, CC, HDIM, HDIM, HDIM, CC, 0, 0, 2, dflag);
}

// Round 6
// 319.641 us; speedup vs baseline: 3.2886x; 1.1348x over previous
//
#include <hip/hip_runtime.h>
#include <hip/hip_bf16.h>

// Problem constants
#define BB 256
#define PP 20
#define HH 4
#define FF 1024
#define LL 300
#define LLP 320           // LL padded to 32-multiple
#define DCAT 1344         // FF + LLP, concatenated node-feature stride
#define SS 16
#define HDIM 1024
#define CC 117
#define NNODE (BB * PP)              // 5120
#define NREAD (BB * (PP * HH - HH))  // 19456
#define EPB 8                        // edges per combine block

typedef __attribute__((ext_vector_type(8))) short bf16x8v;
typedef __attribute__((ext_vector_type(4))) float f32x4v;
typedef __attribute__((ext_vector_type(4))) unsigned short u16x4;

__device__ __forceinline__ float bf2f(unsigned short u) {
  return __uint_as_float((unsigned int)u << 16);
}
__device__ __forceinline__ unsigned short f2b(float f) {
  __hip_bfloat16 h = __float2bfloat16(f);
  return *(unsigned short*)&h;
}

// ---------------------------------------------------------------------------
// Dtype sniff (flag[0]=1 -> inputs are fp32).
// ---------------------------------------------------------------------------
__global__ void sniff_dtype(const unsigned short* __restrict__ buf,
                            int* __restrict__ flag) {
  int t = threadIdx.x;
  int votes = 0;
  for (int i = t; i < 512; i += 256) {
    unsigned int u = (unsigned int)buf[i] << 16;
    float v = __uint_as_float(u);
    float a = fabsf(v);
    if (v == v && a > 9.3e-10f && a < 1.1e9f) votes++;
  }
  __shared__ int sv[256];
  sv[t] = votes;
  __syncthreads();
  for (int s = 128; s > 0; s >>= 1) {
    if (t < s) sv[t] += sv[t + s];
    __syncthreads();
  }
  if (t == 0) flag[0] = (sv[0] < 448) ? 1 : 0;
}

// ---------------------------------------------------------------------------
// Strided vectorized convert: dst[r*dstld + c..c+4) <- src[r*ld + c..], with
// zero col-pad for c>=C. Cp multiple of 4.
// ---------------------------------------------------------------------------
__global__ __launch_bounds__(256) void convert_strided4(
    const void* __restrict__ src, __hip_bfloat16* __restrict__ dst, int R,
    int C, int ld, int Cp, int dstld, const int* __restrict__ flag) {
  const int cp4 = Cp >> 2;
  long i = (long)blockIdx.x * 256 + threadIdx.x;
  if (i >= (long)R * cp4) return;
  int r = (int)(i / cp4), c = (int)(i % cp4) * 4;
  u16x4 o;
  if (flag[0]) {
    if (c + 4 <= C) {
      float4 v = *(const float4*)((const float*)src + (long)r * ld + c);
      o[0] = f2b(v.x); o[1] = f2b(v.y); o[2] = f2b(v.z); o[3] = f2b(v.w);
    } else {
#pragma unroll
      for (int j = 0; j < 4; j++)
        o[j] = (c + j < C) ? f2b(((const float*)src)[(long)r * ld + c + j]) : 0;
    }
  } else {
    const __hip_bfloat16* s = (const __hip_bfloat16*)src;
    if (c + 4 <= C) {
      o = *(const u16x4*)(s + (long)r * ld + c);
    } else {
#pragma unroll
      for (int j = 0; j < 4; j++) {
        unsigned short u = 0;
        if (c + j < C) u = *(const unsigned short*)(s + (long)r * ld + c + j);
        o[j] = u;
      }
    }
  }
  *(u16x4*)(dst + (long)r * dstld + c) = o;
}

// ---------------------------------------------------------------------------
// Small flat converts in one launch: cAv(2048) cAl(600) cB1(1024) cB2(117)
// cW1sp(16x1024 @ W1 flat offset 1324*1024=1355776).
// ---------------------------------------------------------------------------
__global__ __launch_bounds__(256) void convert_smalls(
    const void* __restrict__ s4, const void* __restrict__ s6,
    const void* __restrict__ s7, const void* __restrict__ s8,
    const void* __restrict__ s10, __hip_bfloat16* __restrict__ cAv,
    __hip_bfloat16* __restrict__ cAl, __hip_bfloat16* __restrict__ cB1,
    __hip_bfloat16* __restrict__ cB2, __hip_bfloat16* __restrict__ cW1sp,
    const int* __restrict__ flag) {
  int i = blockIdx.x * 256 + threadIdx.x;
  const int f = flag[0];
  auto rd = [&](const void* p, long idx) -> float {
    return f ? ((const float*)p)[idx]
             : __bfloat162float(((const __hip_bfloat16*)p)[idx]);
  };
  if (i < 2048) cAv[i] = __float2bfloat16(rd(s4, i));
  else if (i < 2648) cAl[i - 2048] = __float2bfloat16(rd(s6, i - 2048));
  else if (i < 3672) cB1[i - 2648] = __float2bfloat16(rd(s8, i - 2648));
  else if (i < 3789) cB2[i - 3672] = __float2bfloat16(rd(s10, i - 3672));
  else if (i < 20173)
    cW1sp[i - 3789] = __float2bfloat16(rd(s7, 1355776L + (i - 3789)));
}

// ---------------------------------------------------------------------------
// All 7 transpose slices in one launch (z descriptor). Writes B^T buffers,
// including the K-concatenated W1Td_cat / W1Ts_cat (dst k-offset + dst ld).
// ---------------------------------------------------------------------------
__global__ __launch_bounds__(256) void transpose_all(
    const void* __restrict__ s3, const void* __restrict__ s5,
    const void* __restrict__ s7, const void* __restrict__ s9,
    __hip_bfloat16* __restrict__ dWvT, __hip_bfloat16* __restrict__ dWlT,
    __hip_bfloat16* __restrict__ dW1d, __hip_bfloat16* __restrict__ dW1s,
    __hip_bfloat16* __restrict__ dW2T, const int* __restrict__ flag) {
  const int z = blockIdx.z;
  const int ROW0[7] = {0, 0, 0, 1024, 1640, 1340, 0};
  const int KK[7]   = {1024, 300, 1024, 300, 1024, 300, 1024};
  const int NN[7]   = {1024, 300, 1024, 1024, 1024, 1024, 117};
  const int LD[7]   = {1024, 300, 1024, 1024, 1024, 1024, 117};
  const int KP[7]   = {1024, 320, 1024, 320, 1024, 320, 1024};
  const int KOFF[7] = {0, 0, 0, 1024, 0, 1024, 0};
  const int KLD[7]  = {1024, 320, DCAT, DCAT, DCAT, DCAT, 1024};
  const void* src = (z == 0) ? s3 : (z == 1) ? s5 : (z == 6) ? s9 : s7;
  __hip_bfloat16* dst = (z == 0) ? dWvT : (z == 1) ? dWlT
                        : (z <= 3) ? dW1d : (z <= 5) ? dW1s : dW2T;
  const int row0 = ROW0[z], K = KK[z], N = NN[z], ld = LD[z], Kp = KP[z];
  const int koff = KOFF[z], kld = KLD[z];
  const int kb = blockIdx.x * 32, nb = blockIdx.y * 32;
  if (kb >= Kp || nb >= N) return;
  __shared__ float tile[32][33];
  const int tx = threadIdx.x & 31, ty = threadIdx.x >> 5;
  const int fl = flag[0];
  for (int i = ty; i < 32; i += 8) {
    int k = kb + i, n = nb + tx;
    float v = 0.f;
    if (k < K && n < N) {
      long idx = (long)(row0 + k) * ld + n;
      v = fl ? ((const float*)src)[idx]
             : __bfloat162float(((const __hip_bfloat16*)src)[idx]);
    }
    tile[i][tx] = v;
  }
  __syncthreads();
  for (int i = ty; i < 32; i += 8) {
    int n = nb + i, k = kb + tx;
    if (n < N && k < Kp)
      dst[(long)n * kld + koff + k] = __float2bfloat16(tile[tx][i]);
  }
}

// ---------------------------------------------------------------------------
// MFMA GEMM (m97 structure): C[M,N] = A[M,K] @ BT[N,K]^T. 128x128 tile,
// BK=32, 4 waves x 4x4 grid of 16x16x32 bf16 MFMA, global_load_lds width=16.
// row_mode=1 gathers A rows r -> (r>>2)*PP + (r&3).
// c_mode: 0 bf16, 1 fp32, 2 branch on outflag[0].
// ---------------------------------------------------------------------------
#define TM 128
#define TN 128
#define TK 32

__global__ __launch_bounds__(256) void gemm_mfma_bt(
    const __hip_bfloat16* __restrict__ A, const __hip_bfloat16* __restrict__ BT,
    void* __restrict__ Cout, const __hip_bfloat16* __restrict__ bias, int M,
    int N, int K, int lda, int ldbt, int ldc, int row_mode, int do_relu,
    int c_mode, const int* __restrict__ outflag) {
  __shared__ __hip_bfloat16 Asm[TM * TK];
  __shared__ __hip_bfloat16 Bsm[TN * TK];
  const int tid = threadIdx.x;
  const int lane = tid & 63;
  const int wave = tid >> 6;
  const int wm = (wave & 1) * 64;
  const int wn = (wave >> 1) * 64;
  const int m0 = blockIdx.y * TM;
  const int n0 = blockIdx.x * TN;
  const int col_l = lane & 15;
  const int quad = lane >> 4;

  f32x4v acc[4][4];
#pragma unroll
  for (int i = 0; i < 4; i++)
#pragma unroll
    for (int j = 0; j < 4; j++)
#pragma unroll
      for (int r = 0; r < 4; r++) acc[i][j][r] = 0.f;

  for (int k0 = 0; k0 < K; k0 += TK) {
#pragma unroll
    for (int p = 0; p < 2; p++) {
      int c = tid + p * 256;
      int r = c >> 2;
      int koff = (c & 3) * 8;
      int row = m0 + r;
      if (row >= M) row = M - 1;
      long grow = row_mode ? ((long)(row >> 2) * PP + (row & 3)) : (long)row;
      const __hip_bfloat16* gp = A + grow * lda + k0 + koff;
      __builtin_amdgcn_global_load_lds(
          (const __attribute__((address_space(1))) unsigned int*)gp,
          (__attribute__((address_space(3))) unsigned int*)(&Asm[c * 8]), 16,
          0, 0);
    }
#pragma unroll
    for (int p = 0; p < 2; p++) {
      int c = tid + p * 256;
      int r = c >> 2;
      int koff = (c & 3) * 8;
      int row = n0 + r;
      if (row >= N) row = N - 1;
      const __hip_bfloat16* gp = BT + (long)row * ldbt + k0 + koff;
      __builtin_amdgcn_global_load_lds(
          (const __attribute__((address_space(1))) unsigned int*)gp,
          (__attribute__((address_space(3))) unsigned int*)(&Bsm[c * 8]), 16,
          0, 0);
    }
    __syncthreads();

    bf16x8v af[4], bf[4];
#pragma unroll
    for (int mi = 0; mi < 4; mi++)
      af[mi] = *(const bf16x8v*)&Asm[(wm + mi * 16 + col_l) * TK + quad * 8];
#pragma unroll
    for (int ni = 0; ni < 4; ni++)
      bf[ni] = *(const bf16x8v*)&Bsm[(wn + ni * 16 + col_l) * TK + quad * 8];
#pragma unroll
    for (int mi = 0; mi < 4; mi++)
#pragma unroll
      for (int ni = 0; ni < 4; ni++)
        acc[mi][ni] = __builtin_amdgcn_mfma_f32_16x16x32_bf16(
            af[mi], bf[ni], acc[mi][ni], 0, 0, 0);
    __syncthreads();
  }

  const int store_f32 = (c_mode == 1) || (c_mode == 2 && outflag && outflag[0]);
#pragma unroll
  for (int mi = 0; mi < 4; mi++) {
    int rbase = m0 + wm + mi * 16 + quad * 4;
#pragma unroll
    for (int ni = 0; ni < 4; ni++) {
      int col = n0 + wn + ni * 16 + col_l;
      if (col >= N) continue;
      float bv = bias ? __bfloat162float(bias[col]) : 0.f;
#pragma unroll
      for (int r = 0; r < 4; r++) {
        int row = rbase + r;
        if (row >= M) continue;
        float v = acc[mi][ni][r] + bv;
        if (do_relu) v = fmaxf(v, 0.f);
        if (store_f32)
          ((float*)Cout)[(long)row * ldc + col] = v;
        else
          ((__hip_bfloat16*)Cout)[(long)row * ldc + col] = __float2bfloat16(v);
      }
    }
  }
}

// ---------------------------------------------------------------------------
// Fused GAT: one block per image. Stages h_cat 20x1344 tile in LDS once;
// computes all 4 logit dots/node (wave-per-node), both segment softmaxes,
// then both messages + residual relu -> new_cat. 1024 threads.
// ---------------------------------------------------------------------------
#define CHROW (DCAT / 4)  // 336 chunks per row

__global__ __launch_bounds__(1024) void attn_fused(
    const __hip_bfloat16* __restrict__ xcat,
    const __hip_bfloat16* __restrict__ hcat,
    const __hip_bfloat16* __restrict__ aV,
    const __hip_bfloat16* __restrict__ aL,
    __hip_bfloat16* __restrict__ newcat) {
  const int b = blockIdx.x;
  const int t = threadIdx.x;
  const long base = (long)b * PP * DCAT;

  __shared__ __hip_bfloat16 hs[PP][DCAT];      // 53,760 B
  __shared__ float esv[PP], edv[PP], esl[PP], edl[PP];
  __shared__ float alphaV[PP * PP], alphaL[PP * PP];  // [s*PP+d]

  // ---- stage h tile (coalesced u16x4)
  for (int i = t; i < PP * CHROW; i += 1024) {
    int r = i / CHROW, c = (i % CHROW) * 4;
    *(u16x4*)&hs[r][c] = *(const u16x4*)(hcat + base + (long)r * DCAT + c);
  }
  __syncthreads();

  // ---- logits: wave w handles nodes w, w+16
  const int wave = t >> 6, lane = t & 63;
  for (int node = wave; node < PP; node += 16) {
    float s1 = 0.f, s2 = 0.f, s3 = 0.f, s4 = 0.f;
    for (int f = lane * 4; f < FF; f += 256) {
      u16x4 hv = *(const u16x4*)&hs[node][f];
      u16x4 a1 = *(const u16x4*)(aV + f);
      u16x4 a2 = *(const u16x4*)(aV + FF + f);
#pragma unroll
      for (int j = 0; j < 4; j++) {
        float hf = bf2f(hv[j]);
        s1 += hf * bf2f(a1[j]);
        s2 += hf * bf2f(a2[j]);
      }
    }
    for (int f = FF + lane * 4; f < FF + LL; f += 256) {
      u16x4 hv = *(const u16x4*)&hs[node][f];
      u16x4 a3 = *(const u16x4*)(aL + (f - FF));
      u16x4 a4 = *(const u16x4*)(aL + LL + (f - FF));
#pragma unroll
      for (int j = 0; j < 4; j++) {
        float hf = bf2f(hv[j]);
        s3 += hf * bf2f(a3[j]);
        s4 += hf * bf2f(a4[j]);
      }
    }
#pragma unroll
    for (int o = 32; o > 0; o >>= 1) {
      s1 += __shfl_down(s1, o);
      s2 += __shfl_down(s2, o);
      s3 += __shfl_down(s3, o);
      s4 += __shfl_down(s4, o);
    }
    if (lane == 0) { esv[node] = s1; edv[node] = s2; esl[node] = s3; edl[node] = s4; }
  }
  __syncthreads();

  // ---- segment softmax: t<40 -> (stream, dst)
  if (t < 2 * PP) {
    const int strm = t / PP, d = t % PP;
    const float* es = strm ? esl : esv;
    const float ed = strm ? edl[d] : edv[d];
    float lg[PP];
    float m = -1e30f;
#pragma unroll
    for (int s = 0; s < PP; s++) {
      float e;
      if (s == d) e = -1e30f;
      else {
        float v = es[s] + ed;
        e = (v > 0.f) ? v : 0.2f * v;  // leaky_relu 0.2
      }
      lg[s] = e;
      m = fmaxf(m, e);
    }
    float sum = 0.f;
#pragma unroll
    for (int s = 0; s < PP; s++) {
      lg[s] = expf(lg[s] - m);
      sum += lg[s];
    }
    float inv = 1.f / (sum + 1e-9f);
    float* al = strm ? alphaL : alphaV;
#pragma unroll
    for (int s = 0; s < PP; s++) al[s * PP + d] = lg[s] * inv;
  }
  __syncthreads();

  // ---- messages + residual relu -> new_cat
  for (int i = t; i < PP * CHROW; i += 1024) {
    int d = i / CHROW, c = (i % CHROW) * 4;
    u16x4 ov;
    if (c >= FF + LL) {           // l-pad chunks: force zero
      ov[0] = 0; ov[1] = 0; ov[2] = 0; ov[3] = 0;
    } else {
      const float* al = (c < FF) ? (alphaV + d) : (alphaL + d);
      float a0 = 0.f, a1 = 0.f, a2 = 0.f, a3 = 0.f;
#pragma unroll
      for (int s = 0; s < PP; s++) {
        float w = al[s * PP];
        u16x4 hv = *(const u16x4*)&hs[s][c];
        a0 += w * bf2f(hv[0]);
        a1 += w * bf2f(hv[1]);
        a2 += w * bf2f(hv[2]);
        a3 += w * bf2f(hv[3]);
      }
      u16x4 xv = *(const u16x4*)(xcat + base + (long)d * DCAT + c);
      ov[0] = f2b(fmaxf(bf2f(xv[0]) + a0, 0.f));
      ov[1] = f2b(fmaxf(bf2f(xv[1]) + a1, 0.f));
      ov[2] = f2b(fmaxf(bf2f(xv[2]) + a2, 0.f));
      ov[3] = f2b(fmaxf(bf2f(xv[3]) + a3, 0.f));
    }
    *(u16x4*)(newcat + base + (long)d * DCAT + c) = ov;
  }
}

// ---------------------------------------------------------------------------
// Combine, 8 edges/block: hdn[e] = relu(Yd[hx] + Ys[s] + sf@W1sp + b1).
// Thread t owns hd slice [4t,4t+4); W1sp slice + bias cached in registers.
// ---------------------------------------------------------------------------
__global__ __launch_bounds__(256) void combine_kernel(
    const int* __restrict__ e_src, const int* __restrict__ e_dst,
    const int* __restrict__ r_eid, const void* __restrict__ spat_raw,
    const __hip_bfloat16* __restrict__ W1sp,
    const __hip_bfloat16* __restrict__ b1,
    const __hip_bfloat16* __restrict__ Yd, const __hip_bfloat16* __restrict__ Ys,
    __hip_bfloat16* __restrict__ hdn, const int* __restrict__ flag) {
  const int t = threadIdx.x;
  const int e0 = blockIdx.x * EPB;
  const int hd = t * 4;

  float w[SS][4];
#pragma unroll
  for (int k = 0; k < SS; k++) {
    u16x4 ww = *(const u16x4*)(W1sp + (long)k * HDIM + hd);
#pragma unroll
    for (int j = 0; j < 4; j++) w[k][j] = bf2f(ww[j]);
  }
  float bb[4];
  {
    u16x4 bv = *(const u16x4*)(b1 + hd);
#pragma unroll
    for (int j = 0; j < 4; j++) bb[j] = bf2f(bv[j]);
  }

  __shared__ int sh_s[EPB], sh_hx[EPB], sh_re[EPB];
  __shared__ float sh_sf[EPB][SS];
  if (t < EPB) {
    int re = r_eid[e0 + t];
    sh_re[t] = re;
    sh_s[t] = e_src[re];
    int d = e_dst[re];
    sh_hx[t] = (d / PP) * HH + (d % PP);
  }
  __syncthreads();
  if (t < EPB * SS) {
    int ee = t >> 4, k = t & 15;
    long idx = (long)sh_re[ee] * SS + k;
    sh_sf[ee][k] = flag[0]
                       ? ((const float*)spat_raw)[idx]
                       : __bfloat162float(((const __hip_bfloat16*)spat_raw)[idx]);
  }
  __syncthreads();

#pragma unroll
  for (int ee = 0; ee < EPB; ee++) {
    const int s = sh_s[ee];
    const int hx = sh_hx[ee];
    u16x4 yd = *(const u16x4*)(Yd + (long)hx * HDIM + hd);
    u16x4 ys = *(const u16x4*)(Ys + (long)s * HDIM + hd);
    float v[4];
#pragma unroll
    for (int j = 0; j < 4; j++) v[j] = bf2f(yd[j]) + bf2f(ys[j]) + bb[j];
#pragma unroll
    for (int k = 0; k < SS; k++) {
      float sfv = sh_sf[ee][k];
#pragma unroll
      for (int j = 0; j < 4; j++) v[j] += sfv * w[k][j];
    }
    u16x4 o;
#pragma unroll
    for (int j = 0; j < 4; j++) o[j] = f2b(fmaxf(v[j], 0.f));
    *(u16x4*)(hdn + (long)(e0 + ee) * HDIM + hd) = o;
  }
}

// ---------------------------------------------------------------------------
extern "C" void kernel_launch(void* const* d_in, const int* in_sizes, int n_in,
                              void* d_out, int out_size, void* d_ws,
                              size_t ws_size, hipStream_t stream) {
  const int* e_src = (const int*)d_in[11];
  const int* e_dst = (const int*)d_in[12];
  const int* r_eid = (const int*)d_in[13];
  (void)ws_size; (void)n_in; (void)in_sizes; (void)out_size;

  char* ws = (char*)d_ws;
  size_t off = 0;
  auto take = [&](size_t bytes) {
    char* p = ws + off;
    off += (bytes + 255) & ~(size_t)255;
    return p;
  };

  int* dflag = (int*)take(256);
  __hip_bfloat16* xcat   = (__hip_bfloat16*)take((size_t)NNODE * DCAT * 2);
  __hip_bfloat16* hcat   = (__hip_bfloat16*)take((size_t)NNODE * DCAT * 2);
  __hip_bfloat16* newcat = (__hip_bfloat16*)take((size_t)NNODE * DCAT * 2);
  __hip_bfloat16* cAv    = (__hip_bfloat16*)take((size_t)2 * FF * 2);
  __hip_bfloat16* cAl    = (__hip_bfloat16*)take((size_t)2 * LL * 2);
  __hip_bfloat16* cB1    = (__hip_bfloat16*)take((size_t)HDIM * 2);
  __hip_bfloat16* cB2    = (__hip_bfloat16*)take((size_t)CC * 2);
  __hip_bfloat16* cW1sp  = (__hip_bfloat16*)take((size_t)SS * HDIM * 2);
  __hip_bfloat16* WvT    = (__hip_bfloat16*)take((size_t)FF * FF * 2);
  __hip_bfloat16* WlT    = (__hip_bfloat16*)take((size_t)LL * LLP * 2);
  __hip_bfloat16* W1Td   = (__hip_bfloat16*)take((size_t)HDIM * DCAT * 2);
  __hip_bfloat16* W1Ts   = (__hip_bfloat16*)take((size_t)HDIM * DCAT * 2);
  __hip_bfloat16* W2T    = (__hip_bfloat16*)take((size_t)CC * HDIM * 2);
  __hip_bfloat16* Yd     = (__hip_bfloat16*)take((size_t)BB * HH * HDIM * 2);
  __hip_bfloat16* Ys     = (__hip_bfloat16*)take((size_t)NNODE * HDIM * 2);
  __hip_bfloat16* hdn    = (__hip_bfloat16*)take((size_t)NREAD * HDIM * 2);

  dim3 blk(256);

  // 0) sniff dtype
  sniff_dtype<<<1, blk, 0, stream>>>((const unsigned short*)d_in[0], dflag);

  // 0b) node features -> xcat (strided concat, zero l-pad)
  {
    long ch = (long)NNODE * (FF / 4);
    convert_strided4<<<(int)((ch + 255) / 256), blk, 0, stream>>>(
        d_in[0], xcat, NNODE, FF, FF, FF, DCAT, dflag);
  }
  {
    long ch = (long)NNODE * (LLP / 4);
    convert_strided4<<<(int)((ch + 255) / 256), blk, 0, stream>>>(
        d_in[1], xcat + FF, NNODE, LL, LL, LLP, DCAT, dflag);
  }
  convert_smalls<<<79, blk, 0, stream>>>(d_in[4], d_in[6], d_in[7], d_in[8],
                                         d_in[10], cAv, cAl, cB1, cB2, cW1sp,
                                         dflag);
  {
    dim3 grid(32, 32, 7);
    transpose_all<<<grid, blk, 0, stream>>>(d_in[3], d_in[5], d_in[7], d_in[9],
                                            WvT, WlT, W1Td, W1Ts, W2T, dflag);
  }

  auto gemm = [&](const __hip_bfloat16* A, const __hip_bfloat16* BT, void* C,
                  const __hip_bfloat16* bias, int M, int N, int K, int lda,
                  int ldbt, int ldc, int row_mode, int relu, int c_mode,
                  const int* oflag) {
    dim3 grid((N + TN - 1) / TN, (M + TM - 1) / TM);
    gemm_mfma_bt<<<grid, blk, 0, stream>>>(A, BT, C, bias, M, N, K, lda, ldbt,
                                           ldc, row_mode, relu, c_mode, oflag);
  };

  // 1) Projections into strided h_cat: h_v cols 0..1024, h_l cols 1024..1324
  gemm(xcat, WvT, hcat, nullptr, NNODE, FF, FF, DCAT, FF, DCAT, 0, 0, 0,
       nullptr);
  gemm(xcat + FF, WlT, hcat + FF, nullptr, NNODE, LL, LLP, DCAT, LLP, DCAT, 0,
       0, 0, nullptr);

  // 2+3) Fused logits + segment-softmax + message + residual relu
  attn_fused<<<BB, dim3(1024), 0, stream>>>(xcat, hcat, cAv, cAl, newcat);

  // 4) Concat-K projections: Yd = gather(new_cat) @ W1Td, Ys = new_cat @ W1Ts
  gemm(newcat, W1Td, Yd, nullptr, BB * HH, HDIM, DCAT, DCAT, DCAT, HDIM, 1, 0,
       0, nullptr);
  gemm(newcat, W1Ts, Ys, nullptr, NNODE, HDIM, DCAT, DCAT, DCAT, HDIM, 0, 0, 0,
       nullptr);

  // 5) Combine + relu -> hdn
  combine_kernel<<<NREAD / EPB, blk, 0, stream>>>(e_src, e_dst, r_eid, d_in[2],
                                                  cW1sp, cB1, Yd, Ys, hdn,
                                                  dflag);

  // 6) out = hdn @ W2 + b2 (dtype per sniffed flag)
  gemm(hdn, W2T, d_out, cB2, NREAD, CC, HDIM, HDIM, HDIM, CC, 0, 0, 2, dflag);
}

// Round 7
// 254.902 us; speedup vs baseline: 4.1238x; 1.2540x over previous
//
#include <hip/hip_runtime.h>
#include <hip/hip_bf16.h>

// Problem constants
#define BB 256
#define PP 20
#define HH 4
#define FF 1024
#define LL 300
#define LLP 320           // LL padded to 32-multiple
#define DCAT 1344         // FF + LLP
#define SS 16
#define HDIM 1024
#define CC 117
#define NNODE (BB * PP)              // 5120
#define NREAD (BB * (PP * HH - HH))  // 19456
#define EPB 8
#define TK 32

typedef __attribute__((ext_vector_type(8))) short bf16x8v;
typedef __attribute__((ext_vector_type(4))) float f32x4v;
typedef __attribute__((ext_vector_type(4))) unsigned short u16x4;

__device__ __forceinline__ float bf2f(unsigned short u) {
  return __uint_as_float((unsigned int)u << 16);
}
__device__ __forceinline__ unsigned short f2b(float f) {
  __hip_bfloat16 h = __float2bfloat16(f);
  return *(unsigned short*)&h;
}

// ---------------------------------------------------------------------------
// Dtype sniff (flag[0]=1 -> inputs are fp32).
// ---------------------------------------------------------------------------
__global__ void sniff_dtype(const unsigned short* __restrict__ buf,
                            int* __restrict__ flag) {
  int t = threadIdx.x;
  int votes = 0;
  for (int i = t; i < 512; i += 256) {
    unsigned int u = (unsigned int)buf[i] << 16;
    float v = __uint_as_float(u);
    float a = fabsf(v);
    if (v == v && a > 9.3e-10f && a < 1.1e9f) votes++;
  }
  __shared__ int sv[256];
  sv[t] = votes;
  __syncthreads();
  for (int s = 128; s > 0; s >>= 1) {
    if (t < s) sv[t] += sv[t + s];
    __syncthreads();
  }
  if (t == 0) flag[0] = (sv[0] < 448) ? 1 : 0;
}

// ---------------------------------------------------------------------------
// Strided vectorized convert with zero col-pad (Cp multiple of 4).
// ---------------------------------------------------------------------------
__global__ __launch_bounds__(256) void convert_strided4(
    const void* __restrict__ src, __hip_bfloat16* __restrict__ dst, int R,
    int C, int ld, int Cp, int dstld, const int* __restrict__ flag) {
  const int cp4 = Cp >> 2;
  long i = (long)blockIdx.x * 256 + threadIdx.x;
  if (i >= (long)R * cp4) return;
  int r = (int)(i / cp4), c = (int)(i % cp4) * 4;
  u16x4 o;
  if (flag[0]) {
    if (c + 4 <= C) {
      float4 v = *(const float4*)((const float*)src + (long)r * ld + c);
      o[0] = f2b(v.x); o[1] = f2b(v.y); o[2] = f2b(v.z); o[3] = f2b(v.w);
    } else {
#pragma unroll
      for (int j = 0; j < 4; j++)
        o[j] = (c + j < C) ? f2b(((const float*)src)[(long)r * ld + c + j]) : 0;
    }
  } else {
    const __hip_bfloat16* s = (const __hip_bfloat16*)src;
    if (c + 4 <= C) {
      o = *(const u16x4*)(s + (long)r * ld + c);
    } else {
#pragma unroll
      for (int j = 0; j < 4; j++) {
        unsigned short u = 0;
        if (c + j < C) u = *(const unsigned short*)(s + (long)r * ld + c + j);
        o[j] = u;
      }
    }
  }
  *(u16x4*)(dst + (long)r * dstld + c) = o;
}

// ---------------------------------------------------------------------------
// Small flat converts in one launch.
// ---------------------------------------------------------------------------
__global__ __launch_bounds__(256) void convert_smalls(
    const void* __restrict__ s4, const void* __restrict__ s6,
    const void* __restrict__ s7, const void* __restrict__ s8,
    const void* __restrict__ s10, __hip_bfloat16* __restrict__ cAv,
    __hip_bfloat16* __restrict__ cAl, __hip_bfloat16* __restrict__ cB1,
    __hip_bfloat16* __restrict__ cB2, __hip_bfloat16* __restrict__ cW1sp,
    const int* __restrict__ flag) {
  int i = blockIdx.x * 256 + threadIdx.x;
  const int f = flag[0];
  auto rd = [&](const void* p, long idx) -> float {
    return f ? ((const float*)p)[idx]
             : __bfloat162float(((const __hip_bfloat16*)p)[idx]);
  };
  if (i < 2048) cAv[i] = __float2bfloat16(rd(s4, i));
  else if (i < 2648) cAl[i - 2048] = __float2bfloat16(rd(s6, i - 2048));
  else if (i < 3672) cB1[i - 2648] = __float2bfloat16(rd(s8, i - 2648));
  else if (i < 3789) cB2[i - 3672] = __float2bfloat16(rd(s10, i - 3672));
  else if (i < 20173)
    cW1sp[i - 3789] = __float2bfloat16(rd(s7, 1355776L + (i - 3789)));
}

// ---------------------------------------------------------------------------
// All 7 transpose slices in one launch (z descriptor); writes B^T buffers,
// including K-concatenated W1Td / W1Ts (dst k-offset + dst ld).
// ---------------------------------------------------------------------------
__global__ __launch_bounds__(256) void transpose_all(
    const void* __restrict__ s3, const void* __restrict__ s5,
    const void* __restrict__ s7, const void* __restrict__ s9,
    __hip_bfloat16* __restrict__ dWvT, __hip_bfloat16* __restrict__ dWlT,
    __hip_bfloat16* __restrict__ dW1d, __hip_bfloat16* __restrict__ dW1s,
    __hip_bfloat16* __restrict__ dW2T, const int* __restrict__ flag) {
  const int z = blockIdx.z;
  const int ROW0[7] = {0, 0, 0, 1024, 1640, 1340, 0};
  const int KK[7]   = {1024, 300, 1024, 300, 1024, 300, 1024};
  const int NN[7]   = {1024, 300, 1024, 1024, 1024, 1024, 117};
  const int LD[7]   = {1024, 300, 1024, 1024, 1024, 1024, 117};
  const int KP[7]   = {1024, 320, 1024, 320, 1024, 320, 1024};
  const int KOFF[7] = {0, 0, 0, 1024, 0, 1024, 0};
  const int KLD[7]  = {1024, 320, DCAT, DCAT, DCAT, DCAT, 1024};
  const void* src = (z == 0) ? s3 : (z == 1) ? s5 : (z == 6) ? s9 : s7;
  __hip_bfloat16* dst = (z == 0) ? dWvT : (z == 1) ? dWlT
                        : (z <= 3) ? dW1d : (z <= 5) ? dW1s : dW2T;
  const int row0 = ROW0[z], K = KK[z], N = NN[z], ld = LD[z], Kp = KP[z];
  const int koff = KOFF[z], kld = KLD[z];
  const int kb = blockIdx.x * 32, nb = blockIdx.y * 32;
  if (kb >= Kp || nb >= N) return;
  __shared__ float tile[32][33];
  const int tx = threadIdx.x & 31, ty = threadIdx.x >> 5;
  const int fl = flag[0];
  for (int i = ty; i < 32; i += 8) {
    int k = kb + i, n = nb + tx;
    float v = 0.f;
    if (k < K && n < N) {
      long idx = (long)(row0 + k) * ld + n;
      v = fl ? ((const float*)src)[idx]
             : __bfloat162float(((const __hip_bfloat16*)src)[idx]);
    }
    tile[i][tx] = v;
  }
  __syncthreads();
  for (int i = ty; i < 32; i += 8) {
    int n = nb + i, k = kb + tx;
    if (n < N && k < Kp)
      dst[(long)n * kld + koff + k] = __float2bfloat16(tile[tx][i]);
  }
}

// ---------------------------------------------------------------------------
// Double-buffered MFMA GEMM, descriptor-merged (blockIdx.z picks d0/d1).
// C = A @ BT^T.  Tile BM x BN, BK=32; waves arranged WR x WC; each wave an
// (BM/WR/16) x (BN/WC/16) grid of 16x16x32 bf16 MFMAs.  Prefetch tile k+1
// into the alternate LDS buffer BEFORE computing tile k — one barrier/iter;
// its vmcnt(0) drain lands after a full compute phase of overlap (low-
// occupancy regime: grids here are only ~1.5 blocks/CU so implicit wave-level
// overlap alone is insufficient — m99/m100's "dbuf neutral" was at 4/CU).
// ---------------------------------------------------------------------------
struct GDesc {
  const __hip_bfloat16* A;
  const __hip_bfloat16* BT;
  void* C;
  const __hip_bfloat16* bias;
  int M, N, K, lda, ldbt, ldc;
  int row_mode, do_relu, c_mode, nbx, nby;
};

template <int BM, int BN, int WR, int WC>
__global__ __launch_bounds__(256) void gemm_db(GDesc d0, GDesc d1,
                                               const int* outflag) {
  constexpr int MI = BM / WR / 16;
  constexpr int NI = BN / WC / 16;
  __shared__ __hip_bfloat16 Asm[2][BM * TK];
  __shared__ __hip_bfloat16 Bsm[2][BN * TK];
  const GDesc d = blockIdx.z ? d1 : d0;
  if ((int)blockIdx.x >= d.nbx || (int)blockIdx.y >= d.nby) return;
  const int tid = threadIdx.x;
  const int lane = tid & 63;
  const int wave = tid >> 6;
  const int wm = (wave % WR) * (BM / WR);
  const int wn = (wave / WR) * (BN / WC);
  const int m0 = blockIdx.y * BM;
  const int n0 = blockIdx.x * BN;
  const int col_l = lane & 15;
  const int quad = lane >> 4;
  const __hip_bfloat16* A = d.A;
  const __hip_bfloat16* BT = d.BT;
  const int M = d.M, N = d.N, lda = d.lda, ldbt = d.ldbt;
  const int row_mode = d.row_mode;

  auto stage = [&](int k0, int buf) {
#pragma unroll
    for (int p = 0; p < BM / 64; p++) {
      int c = tid + p * 256;
      int r = c >> 2;
      int koff = (c & 3) * 8;
      int row = m0 + r;
      if (row >= M) row = M - 1;  // clamp (harmless dup)
      long grow = row_mode ? ((long)(row >> 2) * PP + (row & 3)) : (long)row;
      const __hip_bfloat16* gp = A + grow * lda + k0 + koff;
      __builtin_amdgcn_global_load_lds(
          (const __attribute__((address_space(1))) unsigned int*)gp,
          (__attribute__((address_space(3))) unsigned int*)(&Asm[buf][c * 8]),
          16, 0, 0);
    }
#pragma unroll
    for (int p = 0; p < BN / 64; p++) {
      int c = tid + p * 256;
      int r = c >> 2;
      int koff = (c & 3) * 8;
      int row = n0 + r;
      if (row >= N) row = N - 1;  // garbage cols masked at store
      const __hip_bfloat16* gp = BT + (long)row * ldbt + k0 + koff;
      __builtin_amdgcn_global_load_lds(
          (const __attribute__((address_space(1))) unsigned int*)gp,
          (__attribute__((address_space(3))) unsigned int*)(&Bsm[buf][c * 8]),
          16, 0, 0);
    }
  };

  f32x4v acc[MI][NI];
#pragma unroll
  for (int i = 0; i < MI; i++)
#pragma unroll
    for (int j = 0; j < NI; j++)
#pragma unroll
      for (int r = 0; r < 4; r++) acc[i][j][r] = 0.f;

  const int nk = d.K / TK;
  stage(0, 0);
  __syncthreads();  // vmcnt(0) drain: buf0 ready
  for (int kt = 0; kt < nk; kt++) {
    const int cur = kt & 1;
    if (kt + 1 < nk) stage((kt + 1) * TK, 1 - cur);  // prefetch in flight
    bf16x8v af[MI], bfr[NI];
#pragma unroll
    for (int mi = 0; mi < MI; mi++)
      af[mi] =
          *(const bf16x8v*)&Asm[cur][(wm + mi * 16 + col_l) * TK + quad * 8];
#pragma unroll
    for (int ni = 0; ni < NI; ni++)
      bfr[ni] =
          *(const bf16x8v*)&Bsm[cur][(wn + ni * 16 + col_l) * TK + quad * 8];
#pragma unroll
    for (int mi = 0; mi < MI; mi++)
#pragma unroll
      for (int ni = 0; ni < NI; ni++)
        acc[mi][ni] = __builtin_amdgcn_mfma_f32_16x16x32_bf16(
            af[mi], bfr[ni], acc[mi][ni], 0, 0, 0);
    __syncthreads();  // drains prefetch + protects buffer swap
  }

  const int store_f32 =
      (d.c_mode == 1) || (d.c_mode == 2 && outflag && outflag[0]);
#pragma unroll
  for (int mi = 0; mi < MI; mi++) {
    int rbase = m0 + wm + mi * 16 + quad * 4;
#pragma unroll
    for (int ni = 0; ni < NI; ni++) {
      int col = n0 + wn + ni * 16 + col_l;
      if (col >= N) continue;
      float bv = d.bias ? __bfloat162float(d.bias[col]) : 0.f;
#pragma unroll
      for (int r = 0; r < 4; r++) {
        int row = rbase + r;
        if (row >= M) continue;
        float v = acc[mi][ni][r] + bv;
        if (d.do_relu) v = fmaxf(v, 0.f);
        if (store_f32)
          ((float*)d.C)[(long)row * d.ldc + col] = v;
        else
          ((__hip_bfloat16*)d.C)[(long)row * d.ldc + col] = __float2bfloat16(v);
      }
    }
  }
}

// ---------------------------------------------------------------------------
// Fused GAT: one block per image; h tile in LDS once; logits + segment
// softmax + messages + residual relu. 1024 threads.
// ---------------------------------------------------------------------------
#define CHROW (DCAT / 4)

__global__ __launch_bounds__(1024) void attn_fused(
    const __hip_bfloat16* __restrict__ xcat,
    const __hip_bfloat16* __restrict__ hcat,
    const __hip_bfloat16* __restrict__ aV,
    const __hip_bfloat16* __restrict__ aL,
    __hip_bfloat16* __restrict__ newcat) {
  const int b = blockIdx.x;
  const int t = threadIdx.x;
  const long base = (long)b * PP * DCAT;

  __shared__ __hip_bfloat16 hs[PP][DCAT];
  __shared__ float esv[PP], edv[PP], esl[PP], edl[PP];
  __shared__ float alphaV[PP * PP], alphaL[PP * PP];

  for (int i = t; i < PP * CHROW; i += 1024) {
    int r = i / CHROW, c = (i % CHROW) * 4;
    *(u16x4*)&hs[r][c] = *(const u16x4*)(hcat + base + (long)r * DCAT + c);
  }
  __syncthreads();

  const int wave = t >> 6, lane = t & 63;
  for (int node = wave; node < PP; node += 16) {
    float s1 = 0.f, s2 = 0.f, s3 = 0.f, s4 = 0.f;
    for (int f = lane * 4; f < FF; f += 256) {
      u16x4 hv = *(const u16x4*)&hs[node][f];
      u16x4 a1 = *(const u16x4*)(aV + f);
      u16x4 a2 = *(const u16x4*)(aV + FF + f);
#pragma unroll
      for (int j = 0; j < 4; j++) {
        float hf = bf2f(hv[j]);
        s1 += hf * bf2f(a1[j]);
        s2 += hf * bf2f(a2[j]);
      }
    }
    for (int f = FF + lane * 4; f < FF + LL; f += 256) {
      u16x4 hv = *(const u16x4*)&hs[node][f];
      u16x4 a3 = *(const u16x4*)(aL + (f - FF));
      u16x4 a4 = *(const u16x4*)(aL + LL + (f - FF));
#pragma unroll
      for (int j = 0; j < 4; j++) {
        float hf = bf2f(hv[j]);
        s3 += hf * bf2f(a3[j]);
        s4 += hf * bf2f(a4[j]);
      }
    }
#pragma unroll
    for (int o = 32; o > 0; o >>= 1) {
      s1 += __shfl_down(s1, o);
      s2 += __shfl_down(s2, o);
      s3 += __shfl_down(s3, o);
      s4 += __shfl_down(s4, o);
    }
    if (lane == 0) {
      esv[node] = s1; edv[node] = s2; esl[node] = s3; edl[node] = s4;
    }
  }
  __syncthreads();

  if (t < 2 * PP) {
    const int strm = t / PP, dd = t % PP;
    const float* es = strm ? esl : esv;
    const float ed = strm ? edl[dd] : edv[dd];
    float lg[PP];
    float m = -1e30f;
#pragma unroll
    for (int s = 0; s < PP; s++) {
      float e;
      if (s == dd) e = -1e30f;
      else {
        float v = es[s] + ed;
        e = (v > 0.f) ? v : 0.2f * v;
      }
      lg[s] = e;
      m = fmaxf(m, e);
    }
    float sum = 0.f;
#pragma unroll
    for (int s = 0; s < PP; s++) {
      lg[s] = expf(lg[s] - m);
      sum += lg[s];
    }
    float inv = 1.f / (sum + 1e-9f);
    float* al = strm ? alphaL : alphaV;
#pragma unroll
    for (int s = 0; s < PP; s++) al[s * PP + dd] = lg[s] * inv;
  }
  __syncthreads();

  for (int i = t; i < PP * CHROW; i += 1024) {
    int dd = i / CHROW, c = (i % CHROW) * 4;
    u16x4 ov;
    if (c >= FF + LL) {
      ov[0] = 0; ov[1] = 0; ov[2] = 0; ov[3] = 0;
    } else {
      const float* al = (c < FF) ? (alphaV + dd) : (alphaL + dd);
      float a0 = 0.f, a1 = 0.f, a2 = 0.f, a3 = 0.f;
#pragma unroll
      for (int s = 0; s < PP; s++) {
        float w = al[s * PP];
        u16x4 hv = *(const u16x4*)&hs[s][c];
        a0 += w * bf2f(hv[0]);
        a1 += w * bf2f(hv[1]);
        a2 += w * bf2f(hv[2]);
        a3 += w * bf2f(hv[3]);
      }
      u16x4 xv = *(const u16x4*)(xcat + base + (long)dd * DCAT + c);
      ov[0] = f2b(fmaxf(bf2f(xv[0]) + a0, 0.f));
      ov[1] = f2b(fmaxf(bf2f(xv[1]) + a1, 0.f));
      ov[2] = f2b(fmaxf(bf2f(xv[2]) + a2, 0.f));
      ov[3] = f2b(fmaxf(bf2f(xv[3]) + a3, 0.f));
    }
    *(u16x4*)(newcat + base + (long)dd * DCAT + c) = ov;
  }
}

// ---------------------------------------------------------------------------
// Combine, 8 edges/block: hdn[e] = relu(Yd[hx] + Ys[s] + sf@W1sp + b1).
// ---------------------------------------------------------------------------
__global__ __launch_bounds__(256) void combine_kernel(
    const int* __restrict__ e_src, const int* __restrict__ e_dst,
    const int* __restrict__ r_eid, const void* __restrict__ spat_raw,
    const __hip_bfloat16* __restrict__ W1sp,
    const __hip_bfloat16* __restrict__ b1,
    const __hip_bfloat16* __restrict__ Yd, const __hip_bfloat16* __restrict__ Ys,
    __hip_bfloat16* __restrict__ hdn, const int* __restrict__ flag) {
  const int t = threadIdx.x;
  const int e0 = blockIdx.x * EPB;
  const int hd = t * 4;

  float w[SS][4];
#pragma unroll
  for (int k = 0; k < SS; k++) {
    u16x4 ww = *(const u16x4*)(W1sp + (long)k * HDIM + hd);
#pragma unroll
    for (int j = 0; j < 4; j++) w[k][j] = bf2f(ww[j]);
  }
  float bb[4];
  {
    u16x4 bv = *(const u16x4*)(b1 + hd);
#pragma unroll
    for (int j = 0; j < 4; j++) bb[j] = bf2f(bv[j]);
  }

  __shared__ int sh_s[EPB], sh_hx[EPB], sh_re[EPB];
  __shared__ float sh_sf[EPB][SS];
  if (t < EPB) {
    int re = r_eid[e0 + t];
    sh_re[t] = re;
    sh_s[t] = e_src[re];
    int d = e_dst[re];
    sh_hx[t] = (d / PP) * HH + (d % PP);
  }
  __syncthreads();
  if (t < EPB * SS) {
    int ee = t >> 4, k = t & 15;
    long idx = (long)sh_re[ee] * SS + k;
    sh_sf[ee][k] = flag[0]
                       ? ((const float*)spat_raw)[idx]
                       : __bfloat162float(((const __hip_bfloat16*)spat_raw)[idx]);
  }
  __syncthreads();

#pragma unroll
  for (int ee = 0; ee < EPB; ee++) {
    const int s = sh_s[ee];
    const int hx = sh_hx[ee];
    u16x4 yd = *(const u16x4*)(Yd + (long)hx * HDIM + hd);
    u16x4 ys = *(const u16x4*)(Ys + (long)s * HDIM + hd);
    float v[4];
#pragma unroll
    for (int j = 0; j < 4; j++) v[j] = bf2f(yd[j]) + bf2f(ys[j]) + bb[j];
#pragma unroll
    for (int k = 0; k < SS; k++) {
      float sfv = sh_sf[ee][k];
#pragma unroll
      for (int j = 0; j < 4; j++) v[j] += sfv * w[k][j];
    }
    u16x4 o;
#pragma unroll
    for (int j = 0; j < 4; j++) o[j] = f2b(fmaxf(v[j], 0.f));
    *(u16x4*)(hdn + (long)(e0 + ee) * HDIM + hd) = o;
  }
}

// ---------------------------------------------------------------------------
extern "C" void kernel_launch(void* const* d_in, const int* in_sizes, int n_in,
                              void* d_out, int out_size, void* d_ws,
                              size_t ws_size, hipStream_t stream) {
  const int* e_src = (const int*)d_in[11];
  const int* e_dst = (const int*)d_in[12];
  const int* r_eid = (const int*)d_in[13];
  (void)ws_size; (void)n_in; (void)in_sizes; (void)out_size;

  char* ws = (char*)d_ws;
  size_t off = 0;
  auto take = [&](size_t bytes) {
    char* p = ws + off;
    off += (bytes + 255) & ~(size_t)255;
    return p;
  };

  int* dflag = (int*)take(256);
  __hip_bfloat16* xcat   = (__hip_bfloat16*)take((size_t)NNODE * DCAT * 2);
  __hip_bfloat16* hcat   = (__hip_bfloat16*)take((size_t)NNODE * DCAT * 2);
  __hip_bfloat16* newcat = (__hip_bfloat16*)take((size_t)NNODE * DCAT * 2);
  __hip_bfloat16* cAv    = (__hip_bfloat16*)take((size_t)2 * FF * 2);
  __hip_bfloat16* cAl    = (__hip_bfloat16*)take((size_t)2 * LL * 2);
  __hip_bfloat16* cB1    = (__hip_bfloat16*)take((size_t)HDIM * 2);
  __hip_bfloat16* cB2    = (__hip_bfloat16*)take((size_t)CC * 2);
  __hip_bfloat16* cW1sp  = (__hip_bfloat16*)take((size_t)SS * HDIM * 2);
  __hip_bfloat16* WvT    = (__hip_bfloat16*)take((size_t)FF * FF * 2);
  __hip_bfloat16* WlT    = (__hip_bfloat16*)take((size_t)LL * LLP * 2);
  __hip_bfloat16* W1Td   = (__hip_bfloat16*)take((size_t)HDIM * DCAT * 2);
  __hip_bfloat16* W1Ts   = (__hip_bfloat16*)take((size_t)HDIM * DCAT * 2);
  __hip_bfloat16* W2T    = (__hip_bfloat16*)take((size_t)CC * HDIM * 2);
  __hip_bfloat16* Yd     = (__hip_bfloat16*)take((size_t)BB * HH * HDIM * 2);
  __hip_bfloat16* Ys     = (__hip_bfloat16*)take((size_t)NNODE * HDIM * 2);
  __hip_bfloat16* hdn    = (__hip_bfloat16*)take((size_t)NREAD * HDIM * 2);

  dim3 blk(256);

  // 0) sniff dtype
  sniff_dtype<<<1, blk, 0, stream>>>((const unsigned short*)d_in[0], dflag);

  // 0b) node features -> xcat (strided concat, zero l-pad)
  {
    long ch = (long)NNODE * (FF / 4);
    convert_strided4<<<(int)((ch + 255) / 256), blk, 0, stream>>>(
        d_in[0], xcat, NNODE, FF, FF, FF, DCAT, dflag);
  }
  {
    long ch = (long)NNODE * (LLP / 4);
    convert_strided4<<<(int)((ch + 255) / 256), blk, 0, stream>>>(
        d_in[1], xcat + FF, NNODE, LL, LL, LLP, DCAT, dflag);
  }
  convert_smalls<<<79, blk, 0, stream>>>(d_in[4], d_in[6], d_in[7], d_in[8],
                                         d_in[10], cAv, cAl, cB1, cB2, cW1sp,
                                         dflag);
  {
    dim3 grid(32, 32, 7);
    transpose_all<<<grid, blk, 0, stream>>>(d_in[3], d_in[5], d_in[7], d_in[9],
                                            WvT, WlT, W1Td, W1Ts, W2T, dflag);
  }

  // 1) Projections (merged launch): h_v -> hcat cols 0..1024, h_l -> 1024..1324
  {
    GDesc pv{xcat, WvT, hcat, nullptr,
             NNODE, FF, FF, DCAT, FF, DCAT, 0, 0, 0, 8, 40};
    GDesc pl{xcat + FF, WlT, hcat + FF, nullptr,
             NNODE, LL, LLP, DCAT, LLP, DCAT, 0, 0, 0, 3, 40};
    gemm_db<128, 128, 2, 2><<<dim3(8, 40, 2), blk, 0, stream>>>(pv, pl,
                                                                nullptr);
  }

  // 2+3) Fused logits + segment-softmax + message + residual relu
  attn_fused<<<BB, dim3(1024), 0, stream>>>(xcat, hcat, cAv, cAl, newcat);

  // 4) Concat-K projections (merged launch): Ys = newcat @ W1Ts,
  //    Yd = gather(newcat) @ W1Td
  {
    GDesc gys{newcat, W1Ts, Ys, nullptr,
              NNODE, HDIM, DCAT, DCAT, DCAT, HDIM, 0, 0, 0, 8, 40};
    GDesc gyd{newcat, W1Td, Yd, nullptr,
              BB * HH, HDIM, DCAT, DCAT, DCAT, HDIM, 1, 0, 0, 8, 8};
    gemm_db<128, 128, 2, 2><<<dim3(8, 40, 2), blk, 0, stream>>>(gys, gyd,
                                                                nullptr);
  }

  // 5) Combine + relu -> hdn
  combine_kernel<<<NREAD / EPB, blk, 0, stream>>>(e_src, e_dst, r_eid, d_in[2],
                                                  cW1sp, cB1, Yd, Ys, hdn,
                                                  dflag);

  // 6) out = hdn @ W2 + b2 (64x128 tile: 304 blocks for M=19456, N=117)
  {
    GDesc go{hdn, W2T, d_out, cB2,
             NREAD, CC, HDIM, HDIM, HDIM, CC, 0, 0, 2, 1, 304};
    gemm_db<64, 128, 1, 4><<<dim3(1, 304, 1), blk, 0, stream>>>(go, go, dflag);
  }
}

// Round 8
// 246.678 us; speedup vs baseline: 4.2613x; 1.0333x over previous
//
#include <hip/hip_runtime.h>
#include <hip/hip_bf16.h>

// Problem constants
#define BB 256
#define PP 20
#define HH 4
#define FF 1024
#define LL 300
#define LLP 320           // LL padded to 32-multiple
#define DCAT 1344         // FF + LLP
#define SS 16
#define HDIM 1024
#define CC 117
#define NNODE (BB * PP)              // 5120
#define NREAD (BB * (PP * HH - HH))  // 19456
#define EPB 8
#define TK 32

typedef __attribute__((ext_vector_type(8))) short bf16x8v;
typedef __attribute__((ext_vector_type(4))) float f32x4v;
typedef __attribute__((ext_vector_type(4))) unsigned short u16x4;

__device__ __forceinline__ float bf2f(unsigned short u) {
  return __uint_as_float((unsigned int)u << 16);
}
__device__ __forceinline__ unsigned short f2b(float f) {
  __hip_bfloat16 h = __float2bfloat16(f);
  return *(unsigned short*)&h;
}

// ---------------------------------------------------------------------------
// Dtype sniff (flag[0]=1 -> inputs are fp32).
// ---------------------------------------------------------------------------
__global__ void sniff_dtype(const unsigned short* __restrict__ buf,
                            int* __restrict__ flag) {
  int t = threadIdx.x;
  int votes = 0;
  for (int i = t; i < 512; i += 256) {
    unsigned int u = (unsigned int)buf[i] << 16;
    float v = __uint_as_float(u);
    float a = fabsf(v);
    if (v == v && a > 9.3e-10f && a < 1.1e9f) votes++;
  }
  __shared__ int sv[256];
  sv[t] = votes;
  __syncthreads();
  for (int s = 128; s > 0; s >>= 1) {
    if (t < s) sv[t] += sv[t + s];
    __syncthreads();
  }
  if (t == 0) flag[0] = (sv[0] < 448) ? 1 : 0;
}

// ---------------------------------------------------------------------------
// prep_all: ONE launch for every conversion/transpose (range-dispatched 1-D
// grid; all branches are blockIdx-uniform).
//   [0, 5120)        feat -> xcat cols [0,1024)
//   [5120, 6720)     w2v  -> xcat cols [1024,1344) pad
//   [6720, 6799)     small vectors (aV,aL,b1,b2,W1sp)
//   [6799, 10739)    7 weight transposes -> B^T buffers (32x32 LDS tiles)
// ---------------------------------------------------------------------------
#define NB_FEAT 5120
#define NB_W2V 1600
#define NB_SM 79
#define PREP_BLOCKS 10739

__global__ __launch_bounds__(256) void prep_all(
    const void* __restrict__ s0, const void* __restrict__ s1,
    const void* __restrict__ s3, const void* __restrict__ s4,
    const void* __restrict__ s5, const void* __restrict__ s6,
    const void* __restrict__ s7, const void* __restrict__ s8,
    const void* __restrict__ s9, const void* __restrict__ s10,
    __hip_bfloat16* __restrict__ xcat, __hip_bfloat16* __restrict__ cAv,
    __hip_bfloat16* __restrict__ cAl, __hip_bfloat16* __restrict__ cB1,
    __hip_bfloat16* __restrict__ cB2, __hip_bfloat16* __restrict__ cW1sp,
    __hip_bfloat16* __restrict__ dWvT, __hip_bfloat16* __restrict__ dWlT,
    __hip_bfloat16* __restrict__ dW1d, __hip_bfloat16* __restrict__ dW1s,
    __hip_bfloat16* __restrict__ dW2T, const int* __restrict__ flag) {
  const int bid = blockIdx.x;
  const int t = threadIdx.x;
  const int fl = flag[0];

  if (bid < NB_FEAT) {
    long i = (long)bid * 256 + t;
    int r = (int)(i >> 8);
    int c = ((int)i & 255) * 4;
    u16x4 o;
    if (fl) {
      float4 v = *(const float4*)((const float*)s0 + (long)r * FF + c);
      o[0] = f2b(v.x); o[1] = f2b(v.y); o[2] = f2b(v.z); o[3] = f2b(v.w);
    } else {
      o = *(const u16x4*)((const __hip_bfloat16*)s0 + (long)r * FF + c);
    }
    *(u16x4*)(xcat + (long)r * DCAT + c) = o;
  } else if (bid < NB_FEAT + NB_W2V) {
    long i = (long)(bid - NB_FEAT) * 256 + t;
    int r = (int)(i / 80), c = ((int)(i % 80)) * 4;
    u16x4 o;
    if (c + 4 <= LL) {
      if (fl) {
        const float* p = (const float*)s1 + (long)r * LL + c;
        o[0] = f2b(p[0]); o[1] = f2b(p[1]); o[2] = f2b(p[2]); o[3] = f2b(p[3]);
      } else {
        const __hip_bfloat16* p = (const __hip_bfloat16*)s1 + (long)r * LL + c;
        o[0] = *(const unsigned short*)(p + 0);
        o[1] = *(const unsigned short*)(p + 1);
        o[2] = *(const unsigned short*)(p + 2);
        o[3] = *(const unsigned short*)(p + 3);
      }
    } else {
#pragma unroll
      for (int j = 0; j < 4; j++) {
        float v = 0.f;
        if (c + j < LL)
          v = fl ? ((const float*)s1)[(long)r * LL + c + j]
                 : __bfloat162float(
                       ((const __hip_bfloat16*)s1)[(long)r * LL + c + j]);
        o[j] = f2b(v);
      }
    }
    *(u16x4*)(xcat + (long)r * DCAT + FF + c) = o;
  } else if (bid < NB_FEAT + NB_W2V + NB_SM) {
    int i = (bid - NB_FEAT - NB_W2V) * 256 + t;
    auto rd = [&](const void* p, long idx) -> float {
      return fl ? ((const float*)p)[idx]
                : __bfloat162float(((const __hip_bfloat16*)p)[idx]);
    };
    if (i < 2048) cAv[i] = __float2bfloat16(rd(s4, i));
    else if (i < 2648) cAl[i - 2048] = __float2bfloat16(rd(s6, i - 2048));
    else if (i < 3672) cB1[i - 2648] = __float2bfloat16(rd(s8, i - 2648));
    else if (i < 3789) cB2[i - 3672] = __float2bfloat16(rd(s10, i - 3672));
    else if (i < 20173)
      cW1sp[i - 3789] = __float2bfloat16(rd(s7, 1355776L + (i - 3789)));
  } else {
    int idx = bid - (NB_FEAT + NB_W2V + NB_SM);
    const int OFFS[8] = {0, 1024, 1124, 2148, 2468, 3492, 3812, 3940};
    const int NKB[7] = {32, 10, 32, 10, 32, 10, 32};
    const int ROW0[7] = {0, 0, 0, 1024, 1640, 1340, 0};
    const int KK[7] = {1024, 300, 1024, 300, 1024, 300, 1024};
    const int NN[7] = {1024, 300, 1024, 1024, 1024, 1024, 117};
    const int LD[7] = {1024, 300, 1024, 1024, 1024, 1024, 117};
    const int KP[7] = {1024, 320, 1024, 320, 1024, 320, 1024};
    const int KOFF[7] = {0, 0, 0, 1024, 0, 1024, 0};
    const int KLD[7] = {1024, 320, DCAT, DCAT, DCAT, DCAT, 1024};
    int z = 0;
    while (z < 6 && idx >= OFFS[z + 1]) z++;
    idx -= OFFS[z];
    const int kb = (idx % NKB[z]) * 32, nb = (idx / NKB[z]) * 32;
    const void* src = (z == 0) ? s3 : (z == 1) ? s5 : (z == 6) ? s9 : s7;
    __hip_bfloat16* dst = (z == 0) ? dWvT : (z == 1) ? dWlT
                          : (z <= 3) ? dW1d : (z <= 5) ? dW1s : dW2T;
    const int row0 = ROW0[z], K = KK[z], N = NN[z], ld = LD[z], Kp = KP[z];
    const int koff = KOFF[z], kld = KLD[z];
    __shared__ float tile[32][33];
    const int tx = t & 31, ty = t >> 5;
    for (int i = ty; i < 32; i += 8) {
      int k = kb + i, n = nb + tx;
      float v = 0.f;
      if (k < K && n < N) {
        long sidx = (long)(row0 + k) * ld + n;
        v = fl ? ((const float*)src)[sidx]
               : __bfloat162float(((const __hip_bfloat16*)src)[sidx]);
      }
      tile[i][tx] = v;
    }
    __syncthreads();
    for (int i = ty; i < 32; i += 8) {
      int n = nb + i, k = kb + tx;
      if (n < N && k < Kp)
        dst[(long)n * kld + koff + k] = __float2bfloat16(tile[tx][i]);
    }
  }
}

// ---------------------------------------------------------------------------
// Double-buffered MFMA GEMM, descriptor-merged (blockIdx.z picks d0/d1).
// Small tiles on purpose: ~3 blocks/CU so cross-block wave overlap hides the
// staging drain (m114 co-scheduling).
// ---------------------------------------------------------------------------
struct GDesc {
  const __hip_bfloat16* A;
  const __hip_bfloat16* BT;
  void* C;
  const __hip_bfloat16* bias;
  int M, N, K, lda, ldbt, ldc;
  int row_mode, do_relu, c_mode, nbx, nby;
};

template <int BM, int BN, int WR, int WC>
__global__ __launch_bounds__(256) void gemm_db(GDesc d0, GDesc d1,
                                               const int* outflag) {
  constexpr int MI = BM / WR / 16;
  constexpr int NI = BN / WC / 16;
  __shared__ __hip_bfloat16 Asm[2][BM * TK];
  __shared__ __hip_bfloat16 Bsm[2][BN * TK];
  const GDesc d = blockIdx.z ? d1 : d0;
  if ((int)blockIdx.x >= d.nbx || (int)blockIdx.y >= d.nby) return;
  const int tid = threadIdx.x;
  const int lane = tid & 63;
  const int wave = tid >> 6;
  const int wm = (wave % WR) * (BM / WR);
  const int wn = (wave / WR) * (BN / WC);
  const int m0 = blockIdx.y * BM;
  const int n0 = blockIdx.x * BN;
  const int col_l = lane & 15;
  const int quad = lane >> 4;
  const __hip_bfloat16* A = d.A;
  const __hip_bfloat16* BT = d.BT;
  const int M = d.M, N = d.N, lda = d.lda, ldbt = d.ldbt;
  const int row_mode = d.row_mode;

  auto stage = [&](int k0, int buf) {
#pragma unroll
    for (int c = tid; c < BM * 4; c += 256) {
      int r = c >> 2;
      int koff = (c & 3) * 8;
      int row = m0 + r;
      if (row >= M) row = M - 1;
      long grow = row_mode ? ((long)(row >> 2) * PP + (row & 3)) : (long)row;
      const __hip_bfloat16* gp = A + grow * lda + k0 + koff;
      __builtin_amdgcn_global_load_lds(
          (const __attribute__((address_space(1))) unsigned int*)gp,
          (__attribute__((address_space(3))) unsigned int*)(&Asm[buf][c * 8]),
          16, 0, 0);
    }
#pragma unroll
    for (int c = tid; c < BN * 4; c += 256) {
      int r = c >> 2;
      int koff = (c & 3) * 8;
      int row = n0 + r;
      if (row >= N) row = N - 1;
      const __hip_bfloat16* gp = BT + (long)row * ldbt + k0 + koff;
      __builtin_amdgcn_global_load_lds(
          (const __attribute__((address_space(1))) unsigned int*)gp,
          (__attribute__((address_space(3))) unsigned int*)(&Bsm[buf][c * 8]),
          16, 0, 0);
    }
  };

  f32x4v acc[MI][NI];
#pragma unroll
  for (int i = 0; i < MI; i++)
#pragma unroll
    for (int j = 0; j < NI; j++)
#pragma unroll
      for (int r = 0; r < 4; r++) acc[i][j][r] = 0.f;

  const int nk = d.K / TK;
  stage(0, 0);
  __syncthreads();
  for (int kt = 0; kt < nk; kt++) {
    const int cur = kt & 1;
    if (kt + 1 < nk) stage((kt + 1) * TK, 1 - cur);
    bf16x8v af[MI], bfr[NI];
#pragma unroll
    for (int mi = 0; mi < MI; mi++)
      af[mi] =
          *(const bf16x8v*)&Asm[cur][(wm + mi * 16 + col_l) * TK + quad * 8];
#pragma unroll
    for (int ni = 0; ni < NI; ni++)
      bfr[ni] =
          *(const bf16x8v*)&Bsm[cur][(wn + ni * 16 + col_l) * TK + quad * 8];
#pragma unroll
    for (int mi = 0; mi < MI; mi++)
#pragma unroll
      for (int ni = 0; ni < NI; ni++)
        acc[mi][ni] = __builtin_amdgcn_mfma_f32_16x16x32_bf16(
            af[mi], bfr[ni], acc[mi][ni], 0, 0, 0);
    __syncthreads();
  }

  const int store_f32 =
      (d.c_mode == 1) || (d.c_mode == 2 && outflag && outflag[0]);
#pragma unroll
  for (int mi = 0; mi < MI; mi++) {
    int rbase = m0 + wm + mi * 16 + quad * 4;
#pragma unroll
    for (int ni = 0; ni < NI; ni++) {
      int col = n0 + wn + ni * 16 + col_l;
      if (col >= N) continue;
      float bv = d.bias ? __bfloat162float(d.bias[col]) : 0.f;
#pragma unroll
      for (int r = 0; r < 4; r++) {
        int row = rbase + r;
        if (row >= M) continue;
        float v = acc[mi][ni][r] + bv;
        if (d.do_relu) v = fmaxf(v, 0.f);
        if (store_f32)
          ((float*)d.C)[(long)row * d.ldc + col] = v;
        else
          ((__hip_bfloat16*)d.C)[(long)row * d.ldc + col] = __float2bfloat16(v);
      }
    }
  }
}

// ---------------------------------------------------------------------------
// Fused GAT (unchanged from Round 7).
// ---------------------------------------------------------------------------
#define CHROW (DCAT / 4)

__global__ __launch_bounds__(1024) void attn_fused(
    const __hip_bfloat16* __restrict__ xcat,
    const __hip_bfloat16* __restrict__ hcat,
    const __hip_bfloat16* __restrict__ aV,
    const __hip_bfloat16* __restrict__ aL,
    __hip_bfloat16* __restrict__ newcat) {
  const int b = blockIdx.x;
  const int t = threadIdx.x;
  const long base = (long)b * PP * DCAT;

  __shared__ __hip_bfloat16 hs[PP][DCAT];
  __shared__ float esv[PP], edv[PP], esl[PP], edl[PP];
  __shared__ float alphaV[PP * PP], alphaL[PP * PP];

  for (int i = t; i < PP * CHROW; i += 1024) {
    int r = i / CHROW, c = (i % CHROW) * 4;
    *(u16x4*)&hs[r][c] = *(const u16x4*)(hcat + base + (long)r * DCAT + c);
  }
  __syncthreads();

  const int wave = t >> 6, lane = t & 63;
  for (int node = wave; node < PP; node += 16) {
    float s1 = 0.f, s2 = 0.f, s3 = 0.f, s4 = 0.f;
    for (int f = lane * 4; f < FF; f += 256) {
      u16x4 hv = *(const u16x4*)&hs[node][f];
      u16x4 a1 = *(const u16x4*)(aV + f);
      u16x4 a2 = *(const u16x4*)(aV + FF + f);
#pragma unroll
      for (int j = 0; j < 4; j++) {
        float hf = bf2f(hv[j]);
        s1 += hf * bf2f(a1[j]);
        s2 += hf * bf2f(a2[j]);
      }
    }
    for (int f = FF + lane * 4; f < FF + LL; f += 256) {
      u16x4 hv = *(const u16x4*)&hs[node][f];
      u16x4 a3 = *(const u16x4*)(aL + (f - FF));
      u16x4 a4 = *(const u16x4*)(aL + LL + (f - FF));
#pragma unroll
      for (int j = 0; j < 4; j++) {
        float hf = bf2f(hv[j]);
        s3 += hf * bf2f(a3[j]);
        s4 += hf * bf2f(a4[j]);
      }
    }
#pragma unroll
    for (int o = 32; o > 0; o >>= 1) {
      s1 += __shfl_down(s1, o);
      s2 += __shfl_down(s2, o);
      s3 += __shfl_down(s3, o);
      s4 += __shfl_down(s4, o);
    }
    if (lane == 0) {
      esv[node] = s1; edv[node] = s2; esl[node] = s3; edl[node] = s4;
    }
  }
  __syncthreads();

  if (t < 2 * PP) {
    const int strm = t / PP, dd = t % PP;
    const float* es = strm ? esl : esv;
    const float ed = strm ? edl[dd] : edv[dd];
    float lg[PP];
    float m = -1e30f;
#pragma unroll
    for (int s = 0; s < PP; s++) {
      float e;
      if (s == dd) e = -1e30f;
      else {
        float v = es[s] + ed;
        e = (v > 0.f) ? v : 0.2f * v;
      }
      lg[s] = e;
      m = fmaxf(m, e);
    }
    float sum = 0.f;
#pragma unroll
    for (int s = 0; s < PP; s++) {
      lg[s] = expf(lg[s] - m);
      sum += lg[s];
    }
    float inv = 1.f / (sum + 1e-9f);
    float* al = strm ? alphaL : alphaV;
#pragma unroll
    for (int s = 0; s < PP; s++) al[s * PP + dd] = lg[s] * inv;
  }
  __syncthreads();

  for (int i = t; i < PP * CHROW; i += 1024) {
    int dd = i / CHROW, c = (i % CHROW) * 4;
    u16x4 ov;
    if (c >= FF + LL) {
      ov[0] = 0; ov[1] = 0; ov[2] = 0; ov[3] = 0;
    } else {
      const float* al = (c < FF) ? (alphaV + dd) : (alphaL + dd);
      float a0 = 0.f, a1 = 0.f, a2 = 0.f, a3 = 0.f;
#pragma unroll
      for (int s = 0; s < PP; s++) {
        float w = al[s * PP];
        u16x4 hv = *(const u16x4*)&hs[s][c];
        a0 += w * bf2f(hv[0]);
        a1 += w * bf2f(hv[1]);
        a2 += w * bf2f(hv[2]);
        a3 += w * bf2f(hv[3]);
      }
      u16x4 xv = *(const u16x4*)(xcat + base + (long)dd * DCAT + c);
      ov[0] = f2b(fmaxf(bf2f(xv[0]) + a0, 0.f));
      ov[1] = f2b(fmaxf(bf2f(xv[1]) + a1, 0.f));
      ov[2] = f2b(fmaxf(bf2f(xv[2]) + a2, 0.f));
      ov[3] = f2b(fmaxf(bf2f(xv[3]) + a3, 0.f));
    }
    *(u16x4*)(newcat + base + (long)dd * DCAT + c) = ov;
  }
}

// ---------------------------------------------------------------------------
// Combine, 8 edges/block (unchanged from Round 7).
// ---------------------------------------------------------------------------
__global__ __launch_bounds__(256) void combine_kernel(
    const int* __restrict__ e_src, const int* __restrict__ e_dst,
    const int* __restrict__ r_eid, const void* __restrict__ spat_raw,
    const __hip_bfloat16* __restrict__ W1sp,
    const __hip_bfloat16* __restrict__ b1,
    const __hip_bfloat16* __restrict__ Yd, const __hip_bfloat16* __restrict__ Ys,
    __hip_bfloat16* __restrict__ hdn, const int* __restrict__ flag) {
  const int t = threadIdx.x;
  const int e0 = blockIdx.x * EPB;
  const int hd = t * 4;

  float w[SS][4];
#pragma unroll
  for (int k = 0; k < SS; k++) {
    u16x4 ww = *(const u16x4*)(W1sp + (long)k * HDIM + hd);
#pragma unroll
    for (int j = 0; j < 4; j++) w[k][j] = bf2f(ww[j]);
  }
  float bb[4];
  {
    u16x4 bv = *(const u16x4*)(b1 + hd);
#pragma unroll
    for (int j = 0; j < 4; j++) bb[j] = bf2f(bv[j]);
  }

  __shared__ int sh_s[EPB], sh_hx[EPB], sh_re[EPB];
  __shared__ float sh_sf[EPB][SS];
  if (t < EPB) {
    int re = r_eid[e0 + t];
    sh_re[t] = re;
    sh_s[t] = e_src[re];
    int d = e_dst[re];
    sh_hx[t] = (d / PP) * HH + (d % PP);
  }
  __syncthreads();
  if (t < EPB * SS) {
    int ee = t >> 4, k = t & 15;
    long idx = (long)sh_re[ee] * SS + k;
    sh_sf[ee][k] = flag[0]
                       ? ((const float*)spat_raw)[idx]
                       : __bfloat162float(((const __hip_bfloat16*)spat_raw)[idx]);
  }
  __syncthreads();

#pragma unroll
  for (int ee = 0; ee < EPB; ee++) {
    const int s = sh_s[ee];
    const int hx = sh_hx[ee];
    u16x4 yd = *(const u16x4*)(Yd + (long)hx * HDIM + hd);
    u16x4 ys = *(const u16x4*)(Ys + (long)s * HDIM + hd);
    float v[4];
#pragma unroll
    for (int j = 0; j < 4; j++) v[j] = bf2f(yd[j]) + bf2f(ys[j]) + bb[j];
#pragma unroll
    for (int k = 0; k < SS; k++) {
      float sfv = sh_sf[ee][k];
#pragma unroll
      for (int j = 0; j < 4; j++) v[j] += sfv * w[k][j];
    }
    u16x4 o;
#pragma unroll
    for (int j = 0; j < 4; j++) o[j] = f2b(fmaxf(v[j], 0.f));
    *(u16x4*)(hdn + (long)(e0 + ee) * HDIM + hd) = o;
  }
}

// ---------------------------------------------------------------------------
extern "C" void kernel_launch(void* const* d_in, const int* in_sizes, int n_in,
                              void* d_out, int out_size, void* d_ws,
                              size_t ws_size, hipStream_t stream) {
  const int* e_src = (const int*)d_in[11];
  const int* e_dst = (const int*)d_in[12];
  const int* r_eid = (const int*)d_in[13];
  (void)ws_size; (void)n_in; (void)in_sizes; (void)out_size;

  char* ws = (char*)d_ws;
  size_t off = 0;
  auto take = [&](size_t bytes) {
    char* p = ws + off;
    off += (bytes + 255) & ~(size_t)255;
    return p;
  };

  int* dflag = (int*)take(256);
  __hip_bfloat16* xcat   = (__hip_bfloat16*)take((size_t)NNODE * DCAT * 2);
  __hip_bfloat16* hcat   = (__hip_bfloat16*)take((size_t)NNODE * DCAT * 2);
  __hip_bfloat16* newcat = (__hip_bfloat16*)take((size_t)NNODE * DCAT * 2);
  __hip_bfloat16* cAv    = (__hip_bfloat16*)take((size_t)2 * FF * 2);
  __hip_bfloat16* cAl    = (__hip_bfloat16*)take((size_t)2 * LL * 2);
  __hip_bfloat16* cB1    = (__hip_bfloat16*)take((size_t)HDIM * 2);
  __hip_bfloat16* cB2    = (__hip_bfloat16*)take((size_t)CC * 2);
  __hip_bfloat16* cW1sp  = (__hip_bfloat16*)take((size_t)SS * HDIM * 2);
  __hip_bfloat16* WvT    = (__hip_bfloat16*)take((size_t)FF * FF * 2);
  __hip_bfloat16* WlT    = (__hip_bfloat16*)take((size_t)LL * LLP * 2);
  __hip_bfloat16* W1Td   = (__hip_bfloat16*)take((size_t)HDIM * DCAT * 2);
  __hip_bfloat16* W1Ts   = (__hip_bfloat16*)take((size_t)HDIM * DCAT * 2);
  __hip_bfloat16* W2T    = (__hip_bfloat16*)take((size_t)CC * HDIM * 2);
  __hip_bfloat16* Yd     = (__hip_bfloat16*)take((size_t)BB * HH * HDIM * 2);
  __hip_bfloat16* Ys     = (__hip_bfloat16*)take((size_t)NNODE * HDIM * 2);
  __hip_bfloat16* hdn    = (__hip_bfloat16*)take((size_t)NREAD * HDIM * 2);

  dim3 blk(256);

  // 0) sniff dtype
  sniff_dtype<<<1, blk, 0, stream>>>((const unsigned short*)d_in[0], dflag);

  // 0b) ALL conversions + transposes in one launch
  prep_all<<<PREP_BLOCKS, blk, 0, stream>>>(
      d_in[0], d_in[1], d_in[3], d_in[4], d_in[5], d_in[6], d_in[7], d_in[8],
      d_in[9], d_in[10], xcat, cAv, cAl, cB1, cB2, cW1sp, WvT, WlT, W1Td, W1Ts,
      W2T, dflag);

  // 1) Projections (merged, 64x128 tiles -> ~3.4 blocks/CU)
  {
    GDesc pv{xcat, WvT, hcat, nullptr,
             NNODE, FF, FF, DCAT, FF, DCAT, 0, 0, 0, 8, 80};
    GDesc pl{xcat + FF, WlT, hcat + FF, nullptr,
             NNODE, LL, LLP, DCAT, LLP, DCAT, 0, 0, 0, 3, 80};
    gemm_db<64, 128, 2, 2><<<dim3(8, 80, 2), blk, 0, stream>>>(pv, pl,
                                                               nullptr);
  }

  // 2+3) Fused logits + segment-softmax + message + residual relu
  attn_fused<<<BB, dim3(1024), 0, stream>>>(xcat, hcat, cAv, cAl, newcat);

  // 4) Concat-K projections (merged, 64x128 -> ~3 blocks/CU)
  {
    GDesc gys{newcat, W1Ts, Ys, nullptr,
              NNODE, HDIM, DCAT, DCAT, DCAT, HDIM, 0, 0, 0, 8, 80};
    GDesc gyd{newcat, W1Td, Yd, nullptr,
              BB * HH, HDIM, DCAT, DCAT, DCAT, HDIM, 1, 0, 0, 8, 16};
    gemm_db<64, 128, 2, 2><<<dim3(8, 80, 2), blk, 0, stream>>>(gys, gyd,
                                                               nullptr);
  }

  // 5) Combine + relu -> hdn
  combine_kernel<<<NREAD / EPB, blk, 0, stream>>>(e_src, e_dst, r_eid, d_in[2],
                                                  cW1sp, cB1, Yd, Ys, hdn,
                                                  dflag);

  // 6) out = hdn @ W2 + b2 (32x128 tiles -> 608 blocks ~2.4/CU)
  {
    GDesc go{hdn, W2T, d_out, cB2,
             NREAD, CC, HDIM, HDIM, HDIM, CC, 0, 0, 2, 1, 608};
    gemm_db<32, 128, 1, 4><<<dim3(1, 608, 1), blk, 0, stream>>>(go, go, dflag);
  }
}